// Round 2
// baseline (5858.361 us; speedup 1.0000x reference)
//
#include <hip/hip_runtime.h>
#include <stdint.h>

// AutomatonNetwork: serial 4096-step vecmat chain lifted to a bf16 MFMA matrix
// scan (segment products + tree + boundary-vector descent) + f32 per-segment
// vecmat replay for the emission products.
//
// KEY NUMERICS FIX (round 2): true transfer matrices are row-stochastic, so
// the true state vector has mass exactly 1 at every step. Emission factors are
// computed as (v.p)/(sum v) — dividing by the CURRENT computed mass cancels
// all accumulated bf16 mass drift (which otherwise amplifies into e^{+-O(5)}
// error on prob). Final `internal` likewise normalized to mass 1.
//
// V=128 symbols, N=512 states, L=4096 tokens. SEG=32, G=128 segments.

typedef unsigned short ushort_t;
typedef __attribute__((ext_vector_type(8))) short v8s;    // 8 bf16 (4 VGPRs) MFMA frag
typedef __attribute__((ext_vector_type(4))) float f32x4;  // MFMA 16x16 acc

#define NSTATE 512
#define NSYM   128
#define LTOK   4096
#define SEG    32
#define GSEG   128                       // LTOK/SEG
#define MS     ((size_t)NSTATE*NSTATE)   // elems per matrix (262144)

__device__ __forceinline__ ushort_t f2bf(float f){
  unsigned u = __float_as_uint(f);
  u = u + 0x7FFFu + ((u >> 16) & 1u);    // RNE
  return (ushort_t)(u >> 16);
}
__device__ __forceinline__ float bf2f(ushort_t h){
  return __uint_as_float(((unsigned)h) << 16);
}

// ---------------------------------------------------------------------------
// C[rowbase:rowbase+128, 0:512] = A[rowbase:rowbase+128, :] (bf16 RM)
//                               @ B (given as Bt, n-major / transposed bf16)
// Stores bf16 row-major to dRM, and optionally transposed to dT.
// 256 threads = 4 waves; wave w owns rows [32w,32w+32) of the 128-row strip.
// mfma_f32_16x16x32_bf16 layouts (m89/m120-verified):
//   A: m=lane&15, k=(lane>>4)*8+j ; B: n=lane&15, k=(lane>>4)*8+j
//   D: col=lane&15, row=(lane>>4)*4+i
// Row-block chains are sync-free: row i of C depends only on row i of A
// (B is always a token/tree matrix from a previous launch).
// ---------------------------------------------------------------------------
__device__ void gemm_step(const ushort_t* __restrict__ A,
                          const ushort_t* __restrict__ Bt,
                          ushort_t* __restrict__ dRM,
                          ushort_t* dT, int rowbase){
  __shared__ __align__(16) ushort_t ldsA[128*32];
  __shared__ __align__(16) ushort_t ldsB[128*32];
  const int tid  = threadIdx.x;
  const int lane = tid & 63;
  const int w    = tid >> 6;
  const int l15  = lane & 15;
  const int koff = (lane >> 4) * 8;

  __threadfence_block();   // make prior step's global stores visible block-wide

  for (int p = 0; p < 4; ++p){               // 128-col output panels
    f32x4 acc[2][8];
    #pragma unroll
    for (int rt = 0; rt < 2; ++rt)
      #pragma unroll
      for (int ct = 0; ct < 8; ++ct) acc[rt][ct] = (f32x4){0.f,0.f,0.f,0.f};

    for (int kk = 0; kk < 16; ++kk){         // K in chunks of 32
      __syncthreads();
      for (int idx = tid; idx < 512; idx += 256){
        int rr = idx >> 2, c = idx & 3;
        *(v8s*)&ldsA[rr*32 + c*8] =
            *(const v8s*)&A[(size_t)(rowbase + rr)*NSTATE + kk*32 + c*8];
        *(v8s*)&ldsB[rr*32 + c*8] =
            *(const v8s*)&Bt[(size_t)(p*128 + rr)*NSTATE + kk*32 + c*8];
      }
      __syncthreads();
      v8s a0 = *(const v8s*)&ldsA[(w*32 +      l15)*32 + koff];
      v8s a1 = *(const v8s*)&ldsA[(w*32 + 16 + l15)*32 + koff];
      #pragma unroll
      for (int ct = 0; ct < 8; ++ct){
        v8s b = *(const v8s*)&ldsB[(ct*16 + l15)*32 + koff];
        acc[0][ct] = __builtin_amdgcn_mfma_f32_16x16x32_bf16(a0, b, acc[0][ct], 0,0,0);
        acc[1][ct] = __builtin_amdgcn_mfma_f32_16x16x32_bf16(a1, b, acc[1][ct], 0,0,0);
      }
    }
    const int rb = rowbase + w*32 + (lane >> 4)*4;
    #pragma unroll
    for (int rt = 0; rt < 2; ++rt)
      #pragma unroll
      for (int ct = 0; ct < 8; ++ct)
        #pragma unroll
        for (int i = 0; i < 4; ++i){
          int grow = rb + rt*16 + i;
          int gcol = p*128 + ct*16 + l15;
          ushort_t h = f2bf(acc[rt][ct][i]);
          dRM[(size_t)grow*NSTATE + gcol] = h;
          if (dT) dT[(size_t)gcol*NSTATE + grow] = h;
        }
  }
  __syncthreads();  // drain stores before caller's next chain step reads them
}

// transfer f32 -> Tb (bf16 row-major) and TbT (bf16 transposed)
__global__ __launch_bounds__(256) void k_prep(const float* __restrict__ transfer,
                                              ushort_t* __restrict__ Tb,
                                              ushort_t* __restrict__ TbT){
  __shared__ ushort_t t[32*512];
  const int s = blockIdx.x >> 4;
  const int krows = (blockIdx.x & 15) * 32;
  const int tid = threadIdx.x;
  for (int idx = tid; idx < 32*512; idx += 256){
    int r = idx >> 9, n = idx & 511;
    ushort_t h = f2bf(transfer[(size_t)s*MS + (size_t)(krows + r)*NSTATE + n]);
    Tb[(size_t)s*MS + (size_t)(krows + r)*NSTATE + n] = h;
    t[r*512 + n] = h;
  }
  __syncthreads();
  for (int idx = tid; idx < 512*4; idx += 256){
    int n = idx >> 2, c = idx & 3;
    v8s vv;
    #pragma unroll
    for (int jj = 0; jj < 8; ++jj) vv[jj] = (short)t[(c*8 + jj)*512 + n];
    *(v8s*)&TbT[(size_t)s*MS + (size_t)n*NSTATE + krows + c*8] = vv;
  }
}

// Segment products: WG (g,r) carries rows [128r,128r+128) of segment g's
// running product through 31 chained matmuls. Row-block chains are sync-free.
__global__ __launch_bounds__(256) void k_phase1(const int* __restrict__ tokens,
    const ushort_t* __restrict__ Tb, const ushort_t* __restrict__ TbT,
    ushort_t* Node0, ushort_t* pong, ushort_t* NodeT0){
  const int g = blockIdx.x >> 2;
  const int r = blockIdx.x & 3;
  const int tg = g * SEG;
  ushort_t* selfRM   = Node0 + (size_t)g * MS;   // odd-k buffer (final = M_g)
  ushort_t* selfPong = pong  + (size_t)g * MS;   // even-k buffer
  for (int k = 1; k < SEG; ++k){
    const ushort_t* Asrc = (k == 1) ? (Tb + (size_t)tokens[tg] * MS)
                                    : (((k - 1) & 1) ? selfRM : selfPong);
    ushort_t* dRM = (k & 1) ? selfRM : selfPong;
    ushort_t* dT  = (k == SEG - 1) ? (NodeT0 + (size_t)g * MS) : nullptr;
    const ushort_t* Bt = TbT + (size_t)tokens[tg + k] * MS;
    gemm_step(Asrc, Bt, dRM, dT, r * 128);
  }
}

// One pairwise tree level: Node[dst+j] = Node[src+2j] @ Node[src+2j+1]
__global__ __launch_bounds__(256) void k_tree(ushort_t* Node, ushort_t* NodeT,
                                              int srcOff, int dstOff){
  const int j = blockIdx.x >> 2, r = blockIdx.x & 3;
  const ushort_t* A  = Node  + (size_t)(srcOff + 2*j)     * MS;
  const ushort_t* Bt = NodeT + (size_t)(srcOff + 2*j + 1) * MS;
  ushort_t* dRM = Node  + (size_t)(dstOff + j) * MS;
  ushort_t* dT  = NodeT + (size_t)(dstOff + j) * MS;
  gemm_step(A, Bt, dRM, dT, r * 128);
}

// Boundary vectors: u_g = start @ (prefix of g segment products), via the
// canonical binary decomposition over tree nodes (<=7 f32 vecmats).
// Mass error of u_g is harmless: phase 2 divides by current mass every step.
__global__ __launch_bounds__(512) void k_descent(const float* __restrict__ start,
    const ushort_t* __restrict__ Node, float* __restrict__ u){
  __shared__ float v[NSTATE];
  const int g = blockIdx.x, tid = threadIdx.x;
  v[tid] = start[tid];
  __syncthreads();
  int pos = 0;
  for (int l = 6; l >= 0; --l){
    if ((g >> l) & 1){
      const ushort_t* M = Node + (size_t)((256 - (256 >> l)) + (pos >> l)) * MS;
      float acc = 0.f;
      #pragma unroll 8
      for (int i = 0; i < NSTATE; ++i) acc += v[i] * bf2f(M[(size_t)i*NSTATE + tid]);
      __syncthreads();
      v[tid] = acc;
      __syncthreads();
      pos += 1 << l;
    }
  }
  u[(size_t)g*NSTATE + tid] = v[tid];
}

// Per-segment replay: 32 serial f32 vecmat steps from u_g. Emission factor is
// (v.p)/(sum v): the mass division cancels ALL accumulated bf16 mass drift.
// Last segment emits final `internal`, normalized to mass 1 (true mass).
__global__ __launch_bounds__(512) void k_phase2(const int* __restrict__ tokens,
    const float* __restrict__ u, const ushort_t* __restrict__ Tb,
    const float* __restrict__ probs, float* __restrict__ partials,
    float* __restrict__ out){
  __shared__ float v[NSTATE];
  __shared__ float redc[8], redm[8];
  __shared__ float fac, minv;
  const int g = blockIdx.x, tid = threadIdx.x;
  v[tid] = u[(size_t)g*NSTATE + tid];
  float pp = 1.f;
  __syncthreads();
  for (int k = 0; k < SEG; ++k){
    const int tok = tokens[g*SEG + k];
    float a = v[tid];                                  // mass term
    float b = a * probs[(size_t)tok*NSTATE + tid];     // emission term
    #pragma unroll
    for (int o = 32; o > 0; o >>= 1){
      a += __shfl_down(a, o);
      b += __shfl_down(b, o);
    }
    if ((tid & 63) == 0){ redm[tid >> 6] = a; redc[tid >> 6] = b; }
    __syncthreads();
    if (tid == 0){
      float m = 0.f, c = 0.f;
      #pragma unroll
      for (int q = 0; q < 8; ++q){ m += redm[q]; c += redc[q]; }
      fac = c / m;
    }
    __syncthreads();
    pp *= fac;
    const ushort_t* M = Tb + (size_t)tok * MS;
    float acc = 0.f;
    #pragma unroll 8
    for (int i = 0; i < NSTATE; ++i) acc += v[i] * bf2f(M[(size_t)i*NSTATE + tid]);
    __syncthreads();
    v[tid] = acc;
    __syncthreads();
  }
  if (tid == 0) partials[g] = pp;
  if (g == GSEG - 1){
    // normalize final internal to mass 1 (the true mass)
    float a = v[tid];
    #pragma unroll
    for (int o = 32; o > 0; o >>= 1) a += __shfl_down(a, o);
    if ((tid & 63) == 0) redm[tid >> 6] = a;
    __syncthreads();
    if (tid == 0){
      float m = 0.f;
      #pragma unroll
      for (int q = 0; q < 8; ++q) m += redm[q];
      minv = 1.f / m;
    }
    __syncthreads();
    out[tid] = v[tid] * minv;
  }
}

__global__ __launch_bounds__(512) void k_finish(const float* __restrict__ partials,
    const float* __restrict__ finals, float* out){
  __shared__ float red[8];
  const int tid = threadIdx.x;
  float x = out[tid] * finals[tid];
  #pragma unroll
  for (int o = 32; o > 0; o >>= 1) x += __shfl_down(x, o);
  if ((tid & 63) == 0) red[tid >> 6] = x;
  __syncthreads();
  if (tid == 0){
    float s = 0.f;
    for (int q = 0; q < 8; ++q) s += red[q];
    float pp = 1.f;
    for (int q = 0; q < GSEG; ++q) pp *= partials[q];
    out[NSTATE] = pp * s;
  }
}

// Correct-but-slow fallback (single WG serial f32 chain) if ws_size too small.
__global__ __launch_bounds__(512) void k_fallback(const int* __restrict__ tokens,
    const float* __restrict__ start, const float* __restrict__ transfer,
    const float* __restrict__ probs, const float* __restrict__ finals,
    float* out){
  __shared__ float v[NSTATE];
  __shared__ float red[9];
  const int tid = threadIdx.x;
  v[tid] = start[tid];
  float pp = 1.f;
  __syncthreads();
  for (int t = 0; t < LTOK; ++t){
    const int tok = tokens[t];
    float x = v[tid] * probs[(size_t)tok*NSTATE + tid];
    #pragma unroll
    for (int o = 32; o > 0; o >>= 1) x += __shfl_down(x, o);
    if ((tid & 63) == 0) red[tid >> 6] = x;
    __syncthreads();
    if (tid == 0){
      float c = 0.f;
      for (int q = 0; q < 8; ++q) c += red[q];
      red[8] = c;
    }
    __syncthreads();
    pp *= red[8];
    const float* M = transfer + (size_t)tok * MS;
    float acc = 0.f;
    #pragma unroll 8
    for (int i = 0; i < NSTATE; ++i) acc += v[i] * M[(size_t)i*NSTATE + tid];
    __syncthreads();
    v[tid] = acc;
    __syncthreads();
  }
  out[tid] = v[tid];
  float x = v[tid] * finals[tid];
  #pragma unroll
  for (int o = 32; o > 0; o >>= 1) x += __shfl_down(x, o);
  if ((tid & 63) == 0) red[tid >> 6] = x;
  __syncthreads();
  if (tid == 0){
    float s = 0.f;
    for (int q = 0; q < 8; ++q) s += red[q];
    out[NSTATE] = pp * s;
  }
}

extern "C" void kernel_launch(void* const* d_in, const int* in_sizes, int n_in,
                              void* d_out, int out_size, void* d_ws, size_t ws_size,
                              hipStream_t stream) {
  const int*   tokens   = (const int*)  d_in[0];
  const float* start    = (const float*)d_in[1];
  const float* transfer = (const float*)d_in[2];
  const float* probs    = (const float*)d_in[3];
  const float* finals   = (const float*)d_in[4];
  float* out = (float*)d_out;
  (void)in_sizes; (void)n_in; (void)out_size;

  // Workspace layout (bytes). Node level-0 (128 mats) doubles as the odd-step
  // ping buffer of the phase-1 chains.
  const size_t o_Tb    = 0;
  const size_t o_TbT   = o_Tb    + MS * NSYM * 2;        //  64 MiB
  const size_t o_Node  = o_TbT   + MS * NSYM * 2;        //  64 MiB
  const size_t o_pong  = o_Node  + MS * 254  * 2;        // 127 MiB (levels 0..6)
  const size_t o_NodeT = o_pong  + MS * GSEG * 2;        //  64 MiB
  const size_t o_u     = o_NodeT + MS * 254  * 2;        // 127 MiB
  const size_t o_part  = o_u     + (size_t)GSEG * NSTATE * 4;
  const size_t NEED    = o_part  + GSEG * 4;

  if (ws_size < NEED){
    k_fallback<<<1, 512, 0, stream>>>(tokens, start, transfer, probs, finals, out);
    return;
  }
  char* ws = (char*)d_ws;
  ushort_t* Tb    = (ushort_t*)(ws + o_Tb);
  ushort_t* TbT   = (ushort_t*)(ws + o_TbT);
  ushort_t* Node  = (ushort_t*)(ws + o_Node);
  ushort_t* pong  = (ushort_t*)(ws + o_pong);
  ushort_t* NodeT = (ushort_t*)(ws + o_NodeT);
  float*    u     = (float*)   (ws + o_u);
  float*    parts = (float*)   (ws + o_part);

  k_prep  <<<NSYM * 16, 256, 0, stream>>>(transfer, Tb, TbT);
  k_phase1<<<GSEG * 4,  256, 0, stream>>>(tokens, Tb, TbT, Node, pong, NodeT);
  for (int l = 1; l <= 6; ++l){
    const int cnt    = GSEG >> l;
    const int srcOff = 256 - (256 >> (l - 1));
    const int dstOff = 256 - (256 >> l);
    k_tree<<<cnt * 4, 256, 0, stream>>>(Node, NodeT, srcOff, dstOff);
  }
  k_descent<<<GSEG, 512, 0, stream>>>(start, Node, u);
  k_phase2 <<<GSEG, 512, 0, stream>>>(tokens, u, Tb, probs, parts, out);
  k_finish <<<1,    512, 0, stream>>>(parts, finals, out);
}

// Round 3
// 5284.909 us; speedup vs baseline: 1.1085x; 1.1085x over previous
//
#include <hip/hip_runtime.h>
#include <stdint.h>

// AutomatonNetwork: 4096-step vecmat chain lifted to a bf16 MFMA *binary
// product tree* + boundary-vector descent + f32 per-segment replay.
//
// Round-3 changes vs round-2 (which passed, absmax 1.5e-5, 5858 us):
//  * phase1 31-deep chains -> unified binary tree: chains of W tokens
//    (W in {8,16,32} picked by ws_size) then pairwise tree levels to L11.
//    Same total matmuls (4094); bottom-stage parallelism 512 -> 2048 WGs.
//  * parity-form node storage (even idx = row-major, odd idx = transposed):
//    every GEMM A-operand is an even node, every B-operand odd, and descent
//    provably reads only even nodes -> one form per node, half the writes.
//  * gemm_step: BK=64 (half the barriers) + __builtin_amdgcn_global_load_lds
//    width-16 async staging (no VGPR round-trip).
// Numerics: emission factors (v.p)/(sum v) cancel bf16 mass drift (proven).

typedef unsigned short ushort_t;
typedef __attribute__((ext_vector_type(8))) short v8s;    // 8 bf16 MFMA frag
typedef __attribute__((ext_vector_type(4))) float f32x4;  // MFMA 16x16 acc

#define NSTATE 512
#define NSYM   128
#define LTOK   4096
#define SEG    32
#define GSEG   128
#define MS     ((size_t)NSTATE*NSTATE)

__device__ __forceinline__ ushort_t f2bf(float f){
  unsigned u = __float_as_uint(f);
  u = u + 0x7FFFu + ((u >> 16) & 1u);    // RNE
  return (ushort_t)(u >> 16);
}
__device__ __forceinline__ float bf2f(ushort_t h){
  return __uint_as_float(((unsigned)h) << 16);
}

__device__ __forceinline__ void gl_lds16(const void* g, void* l){
  __builtin_amdgcn_global_load_lds(
      (const __attribute__((address_space(1))) unsigned int*)g,
      (__attribute__((address_space(3))) unsigned int*)l, 16, 0, 0);
}

// ---------------------------------------------------------------------------
// C[rowbase:+128, 0:512] = A[rowbase:+128, :] (bf16 RM) @ B (as Bt, n-major).
// Stores bf16 RM to dRM and/or transposed to dT (either may be null).
// 256 thr = 4 waves; wave w owns rows [32w,32w+32). BK=64, 4 col panels.
// mfma_f32_16x16x32_bf16: A m=lane&15,k=(lane>>4)*8+j; B n=lane&15,same k;
// D col=lane&15, row=(lane>>4)*4+i.  (HW-verified layouts, round-2-proven.)
// ---------------------------------------------------------------------------
__device__ void gemm_step(const ushort_t* __restrict__ A,
                          const ushort_t* __restrict__ Bt,
                          ushort_t* dRM, ushort_t* dT, int rowbase){
  __shared__ __align__(16) ushort_t ldsA[128*64];
  __shared__ __align__(16) ushort_t ldsB[128*64];
  const int tid  = threadIdx.x;
  const int lane = tid & 63;
  const int w    = tid >> 6;
  const int l15  = lane & 15;
  const int koff = (lane >> 4) * 8;

  __threadfence_block();   // chain steps: make prior global stores visible

  for (int p = 0; p < 4; ++p){               // 128-col output panels
    f32x4 acc[2][8];
    #pragma unroll
    for (int rt = 0; rt < 2; ++rt)
      #pragma unroll
      for (int ct = 0; ct < 8; ++ct) acc[rt][ct] = (f32x4){0.f,0.f,0.f,0.f};

    for (int kk = 0; kk < 8; ++kk){          // K in chunks of 64
      __syncthreads();
      #pragma unroll
      for (int q = 0; q < 4; ++q){           // stage 128x64 A and B tiles
        int idx = tid + q*256;               // lds dest = base + lane*16 (OK)
        int rr = idx >> 3, c = idx & 7;
        gl_lds16(&A [(size_t)(rowbase + rr)*NSTATE + kk*64 + c*8], &ldsA[idx*8]);
        gl_lds16(&Bt[(size_t)(p*128   + rr)*NSTATE + kk*64 + c*8], &ldsB[idx*8]);
      }
      __syncthreads();                       // compiler drains vmcnt here
      #pragma unroll
      for (int kc = 0; kc < 2; ++kc){
        v8s a0 = *(const v8s*)&ldsA[(w*32 +      l15)*64 + kc*32 + koff];
        v8s a1 = *(const v8s*)&ldsA[(w*32 + 16 + l15)*64 + kc*32 + koff];
        #pragma unroll
        for (int ct = 0; ct < 8; ++ct){
          v8s b = *(const v8s*)&ldsB[(ct*16 + l15)*64 + kc*32 + koff];
          acc[0][ct] = __builtin_amdgcn_mfma_f32_16x16x32_bf16(a0, b, acc[0][ct], 0,0,0);
          acc[1][ct] = __builtin_amdgcn_mfma_f32_16x16x32_bf16(a1, b, acc[1][ct], 0,0,0);
        }
      }
    }
    const int rb = rowbase + w*32 + (lane >> 4)*4;
    #pragma unroll
    for (int rt = 0; rt < 2; ++rt)
      #pragma unroll
      for (int ct = 0; ct < 8; ++ct)
        #pragma unroll
        for (int i = 0; i < 4; ++i){
          int grow = rb + rt*16 + i;
          int gcol = p*128 + ct*16 + l15;
          ushort_t h = f2bf(acc[rt][ct][i]);
          if (dRM) dRM[(size_t)grow*NSTATE + gcol] = h;
          if (dT)  dT [(size_t)gcol*NSTATE + grow] = h;
        }
  }
  __syncthreads();  // drain stores before caller's next chain step
}

// transfer f32 -> Tb (bf16 row-major) and TbT (bf16 transposed)
__global__ __launch_bounds__(256) void k_prep(const float* __restrict__ transfer,
                                              ushort_t* __restrict__ Tb,
                                              ushort_t* __restrict__ TbT){
  __shared__ ushort_t t[32*512];
  const int s = blockIdx.x >> 4;
  const int krows = (blockIdx.x & 15) * 32;
  const int tid = threadIdx.x;
  for (int idx = tid; idx < 32*512; idx += 256){
    int r = idx >> 9, n = idx & 511;
    ushort_t h = f2bf(transfer[(size_t)s*MS + (size_t)(krows + r)*NSTATE + n]);
    Tb[(size_t)s*MS + (size_t)(krows + r)*NSTATE + n] = h;
    t[r*512 + n] = h;
  }
  __syncthreads();
  for (int idx = tid; idx < 512*4; idx += 256){
    int n = idx >> 2, c = idx & 3;
    v8s vv;
    #pragma unroll
    for (int jj = 0; jj < 8; ++jj) vv[jj] = (short)t[(c*8 + jj)*512 + n];
    *(v8s*)&TbT[(size_t)s*MS + (size_t)n*NSTATE + krows + c*8] = vv;
  }
}

// Chains: WG (c,r) carries rows [128r,+128) of chain c's product of W tokens
// through W-1 chained matmuls (row-block chains are sync-free). Final product
// -> Lout[c] in parity form (even c: RM, odd c: transposed).
__global__ __launch_bounds__(256) void k_chain(const int* __restrict__ tokens,
    const ushort_t* __restrict__ Tb, const ushort_t* __restrict__ TbT,
    ushort_t* ping, ushort_t* pong, ushort_t* Lout, int W){
  const int c = blockIdx.x >> 2;
  const int r = blockIdx.x & 3;
  const int t0 = c * W;
  ushort_t* bufA = ping + (size_t)c * MS;   // odd-k dest
  ushort_t* bufB = pong + (size_t)c * MS;   // even-k dest
  for (int k = 1; k < W; ++k){
    const ushort_t* Asrc = (k == 1) ? Tb + (size_t)tokens[t0] * MS
                                    : (((k - 1) & 1) ? bufA : bufB);
    ushort_t *dRM, *dT;
    if (k == W - 1){
      ushort_t* slot = Lout + (size_t)c * MS;
      dRM = (c & 1) ? nullptr : slot;
      dT  = (c & 1) ? slot    : nullptr;
    } else {
      dRM = (k & 1) ? bufA : bufB; dT = nullptr;
    }
    gemm_step(Asrc, TbT + (size_t)tokens[t0 + k] * MS, dRM, dT, r * 128);
  }
}

// One tree level: Ldst[j] = Lsrc[2j] (RM) @ Lsrc[2j+1] (T); dst parity form.
__global__ __launch_bounds__(256) void k_tree(const ushort_t* __restrict__ Lsrc,
                                              ushort_t* __restrict__ Ldst){
  const int j = blockIdx.x >> 2, r = blockIdx.x & 3;
  const ushort_t* A  = Lsrc + (size_t)(2*j)     * MS;
  const ushort_t* Bt = Lsrc + (size_t)(2*j + 1) * MS;
  ushort_t* slot = Ldst + (size_t)j * MS;
  gemm_step(A, Bt, (j & 1) ? nullptr : slot, (j & 1) ? slot : nullptr, r * 128);
}

// Boundary vectors u_g via binary decomposition over tree levels 5..11.
// Node index (pos>>l) is always even -> RM form available. Mass error in u_g
// is harmless (phase 2 renormalizes every step).
__global__ __launch_bounds__(512) void k_descent(const float* __restrict__ start,
    const ushort_t* __restrict__ Upper, float* __restrict__ u){
  __shared__ float v[NSTATE];
  const int base5[7] = {0,128,192,224,240,248,252};  // level 5..11 offsets
  const int g = blockIdx.x, tid = threadIdx.x;
  v[tid] = start[tid];
  __syncthreads();
  int pos = 0;
  for (int l = 6; l >= 0; --l){
    if ((g >> l) & 1){
      const ushort_t* M = Upper + (size_t)(base5[l] + (pos >> l)) * MS;
      float acc = 0.f;
      #pragma unroll 8
      for (int i = 0; i < NSTATE; ++i) acc += v[i] * bf2f(M[(size_t)i*NSTATE + tid]);
      __syncthreads();
      v[tid] = acc;
      __syncthreads();
      pos += 1 << l;
    }
  }
  u[(size_t)g*NSTATE + tid] = v[tid];
}

// Per-segment replay: 32 serial f32 vecmat steps from u_g. Emission factor
// (v.p)/(sum v) cancels accumulated bf16 mass drift. g=127 emits `internal`
// normalized to mass 1.
__global__ __launch_bounds__(512) void k_phase2(const int* __restrict__ tokens,
    const float* __restrict__ u, const ushort_t* __restrict__ Tb,
    const float* __restrict__ probs, float* __restrict__ partials,
    float* __restrict__ out){
  __shared__ float v[NSTATE];
  __shared__ float redc[8], redm[8];
  __shared__ float fac, minv;
  const int g = blockIdx.x, tid = threadIdx.x;
  v[tid] = u[(size_t)g*NSTATE + tid];
  float pp = 1.f;
  __syncthreads();
  for (int k = 0; k < SEG; ++k){
    const int tok = tokens[g*SEG + k];
    float a = v[tid];
    float b = a * probs[(size_t)tok*NSTATE + tid];
    #pragma unroll
    for (int o = 32; o > 0; o >>= 1){
      a += __shfl_down(a, o);
      b += __shfl_down(b, o);
    }
    if ((tid & 63) == 0){ redm[tid >> 6] = a; redc[tid >> 6] = b; }
    __syncthreads();
    if (tid == 0){
      float m = 0.f, c = 0.f;
      #pragma unroll
      for (int q = 0; q < 8; ++q){ m += redm[q]; c += redc[q]; }
      fac = c / m;
    }
    __syncthreads();
    pp *= fac;
    const ushort_t* M = Tb + (size_t)tok * MS;
    float acc = 0.f;
    #pragma unroll 8
    for (int i = 0; i < NSTATE; ++i) acc += v[i] * bf2f(M[(size_t)i*NSTATE + tid]);
    __syncthreads();
    v[tid] = acc;
    __syncthreads();
  }
  if (tid == 0) partials[g] = pp;
  if (g == GSEG - 1){
    float a = v[tid];
    #pragma unroll
    for (int o = 32; o > 0; o >>= 1) a += __shfl_down(a, o);
    if ((tid & 63) == 0) redm[tid >> 6] = a;
    __syncthreads();
    if (tid == 0){
      float m = 0.f;
      #pragma unroll
      for (int q = 0; q < 8; ++q) m += redm[q];
      minv = 1.f / m;
    }
    __syncthreads();
    out[tid] = v[tid] * minv;
  }
}

__global__ __launch_bounds__(512) void k_finish(const float* __restrict__ partials,
    const float* __restrict__ finals, float* out){
  __shared__ float red[8];
  const int tid = threadIdx.x;
  float x = out[tid] * finals[tid];
  #pragma unroll
  for (int o = 32; o > 0; o >>= 1) x += __shfl_down(x, o);
  if ((tid & 63) == 0) red[tid >> 6] = x;
  __syncthreads();
  if (tid == 0){
    float s = 0.f;
    for (int q = 0; q < 8; ++q) s += red[q];
    float pp = 1.f;
    for (int q = 0; q < GSEG; ++q) pp *= partials[q];
    out[NSTATE] = pp * s;
  }
}

// Correct-but-slow fallback (single WG serial f32 chain) if ws_size too small.
__global__ __launch_bounds__(512) void k_fallback(const int* __restrict__ tokens,
    const float* __restrict__ start, const float* __restrict__ transfer,
    const float* __restrict__ probs, const float* __restrict__ finals,
    float* out){
  __shared__ float v[NSTATE];
  __shared__ float red[9];
  const int tid = threadIdx.x;
  v[tid] = start[tid];
  float pp = 1.f;
  __syncthreads();
  for (int t = 0; t < LTOK; ++t){
    const int tok = tokens[t];
    float x = v[tid] * probs[(size_t)tok*NSTATE + tid];
    #pragma unroll
    for (int o = 32; o > 0; o >>= 1) x += __shfl_down(x, o);
    if ((tid & 63) == 0) red[tid >> 6] = x;
    __syncthreads();
    if (tid == 0){
      float c = 0.f;
      for (int q = 0; q < 8; ++q) c += red[q];
      red[8] = c;
    }
    __syncthreads();
    pp *= red[8];
    const float* M = transfer + (size_t)tok * MS;
    float acc = 0.f;
    #pragma unroll 8
    for (int i = 0; i < NSTATE; ++i) acc += v[i] * M[(size_t)i*NSTATE + tid];
    __syncthreads();
    v[tid] = acc;
    __syncthreads();
  }
  out[tid] = v[tid];
  float x = v[tid] * finals[tid];
  #pragma unroll
  for (int o = 32; o > 0; o >>= 1) x += __shfl_down(x, o);
  if ((tid & 63) == 0) red[tid >> 6] = x;
  __syncthreads();
  if (tid == 0){
    float s = 0.f;
    for (int q = 0; q < 8; ++q) s += red[q];
    out[NSTATE] = pp * s;
  }
}

extern "C" void kernel_launch(void* const* d_in, const int* in_sizes, int n_in,
                              void* d_out, int out_size, void* d_ws, size_t ws_size,
                              hipStream_t stream) {
  const int*   tokens   = (const int*)  d_in[0];
  const float* start    = (const float*)d_in[1];
  const float* transfer = (const float*)d_in[2];
  const float* probs    = (const float*)d_in[3];
  const float* finals   = (const float*)d_in[4];
  float* out = (float*)d_out;
  (void)in_sizes; (void)n_in; (void)out_size;

  const size_t C2 = MS * 2;                        // bytes per matrix form
  // common layout
  size_t off = 0;
  const size_t o_Tb    = off; off += C2 * NSYM;    // 64 MiB
  const size_t o_TbT   = off; off += C2 * NSYM;    // 64 MiB
  const size_t o_Upper = off; off += C2 * 254;     // 127 MiB (levels 5..11)
  const size_t o_u     = off; off += (size_t)GSEG * NSTATE * 4;
  const size_t o_part  = off; off += GSEG * 4 + 256;
  const size_t common  = off;

  const size_t need8  = common + C2 * (512 + 512 + 512 + 256); // ping,pong,L3,L4
  const size_t need16 = common + C2 * (256 + 256 + 256);       // ping,pong,L4
  const size_t need32 = common + C2 * (128 + 128);             // ping,pong

  int W;
  if      (ws_size >= need8)  W = 8;
  else if (ws_size >= need16) W = 16;
  else if (ws_size >= need32) W = 32;
  else {
    k_fallback<<<1, 512, 0, stream>>>(tokens, start, transfer, probs, finals, out);
    return;
  }
  const int nchain = LTOK / W;
  const int sLvl   = (W == 8) ? 3 : (W == 16) ? 4 : 5;

  char* ws = (char*)d_ws;
  ushort_t* Tb    = (ushort_t*)(ws + o_Tb);
  ushort_t* TbT   = (ushort_t*)(ws + o_TbT);
  ushort_t* Upper = (ushort_t*)(ws + o_Upper);
  float*    u     = (float*)   (ws + o_u);
  float*    parts = (float*)   (ws + o_part);

  size_t oo = common;
  ushort_t* ping = (ushort_t*)(ws + oo); oo += C2 * nchain;
  ushort_t* pong = (ushort_t*)(ws + oo); oo += C2 * nchain;
  ushort_t* L3buf = nullptr, *L4buf = nullptr;
  if (W == 8) { L3buf = (ushort_t*)(ws + oo); oo += C2 * 512; }
  if (W <= 16){ L4buf = (ushort_t*)(ws + oo); oo += C2 * 256; }

  // level pointer table (tree levels 3..11); levels >=5 live in Upper
  const int upOff[7] = {0,128,192,224,240,248,252};
  ushort_t* lvl[12] = {nullptr};
  lvl[3] = L3buf; lvl[4] = L4buf;
  for (int l = 5; l <= 11; ++l) lvl[l] = Upper + (size_t)upOff[l-5] * MS;

  k_prep <<<NSYM * 16, 256, 0, stream>>>(transfer, Tb, TbT);
  k_chain<<<nchain * 4, 256, 0, stream>>>(tokens, Tb, TbT, ping, pong, lvl[sLvl], W);
  for (int l = sLvl; l < 11; ++l){
    const int cntNext = LTOK >> (l + 1);           // nodes at level l+1
    k_tree<<<cntNext * 4, 256, 0, stream>>>(lvl[l], lvl[l + 1]);
  }
  k_descent<<<GSEG, 512, 0, stream>>>(start, Upper, u);
  k_phase2 <<<GSEG, 512, 0, stream>>>(tokens, u, Tb, probs, parts, out);
  k_finish <<<1,    512, 0, stream>>>(parts, finals, out);
}

// Round 4
// 4777.883 us; speedup vs baseline: 1.2261x; 1.1061x over previous
//
#include <hip/hip_runtime.h>
#include <stdint.h>

// AutomatonNetwork: 4096-step vecmat chain lifted to a bf16 MFMA product tree.
// Round-4: LDS-resident chain strips. Each WG holds its 128x512 running
// product strip in LDS (128 KiB) across all W-1 chain steps; only B tiles
// (32 KiB) stream from global (register-prefetched, ds_write-staged,
// XOR-swizzled against bank conflicts). Eliminates the 9 GB of intermediate
// HBM traffic that made round-3 HBM-bound (3.4 TB/s, MfmaUtil 10%).
// Requires 160 KiB dynamic LDS (hipFuncSetAttribute); falls back to the
// proven round-3 global-intermediate path if rejected.
// Numerics: emission factors (v.p)/(sum v) cancel bf16 mass drift (proven,
// absmax 1.5e-5 vs 4e-3 threshold).

typedef unsigned short ushort_t;
typedef __attribute__((ext_vector_type(8))) short v8s;    // 8 bf16 MFMA frag
typedef __attribute__((ext_vector_type(4))) float f32x4;  // MFMA 16x16 acc

#define NSTATE 512
#define NSYM   128
#define LTOK   4096
#define SEG    32
#define GSEG   128
#define MS     ((size_t)NSTATE*NSTATE)

__device__ __forceinline__ ushort_t f2bf(float f){
  unsigned u = __float_as_uint(f);
  u = u + 0x7FFFu + ((u >> 16) & 1u);    // RNE
  return (ushort_t)(u >> 16);
}
__device__ __forceinline__ float bf2f(ushort_t h){
  return __uint_as_float(((unsigned)h) << 16);
}

// ---------------------------------------------------------------------------
// LDS-resident chain kernel. WG (c, r) owns rows [128r,+128) of chain c's
// running product, kept in LDS for all W-1 steps. 512 thr = 8 waves:
// wave = (rhalf 0..1) x (panel 0..3) -> 64 rows x 128 cols, acc 128 f32/lane.
// Swizzles: A chunk^( row&7 ) over 64 chunks/row; B chunk^((n+(n>>2))&3)
// over 4 chunks/row -> fragment reads spread across banks (2-way = free).
// mfma_f32_16x16x32_bf16: A m=lane&15,k=(lane>>4)*8+j; B n=lane&15 same k;
// D col=lane&15,row=(lane>>4)*4+i (HW-verified, rounds 2-3 proven).
// ---------------------------------------------------------------------------
__global__ __launch_bounds__(512, 2) void k_chain_lds(
    const int* __restrict__ tokens, const ushort_t* __restrict__ Tb,
    const ushort_t* __restrict__ TbT, ushort_t* __restrict__ Lout, int W){
  extern __shared__ __align__(16) ushort_t lds[];
  ushort_t* As = lds;                 // 128 rows x 512 (64 chunks of 8, swz)
  ushort_t* Bs = lds + 128*512;       // 512 rows x 32 (4 chunks of 8, swz)
  const int c       = blockIdx.x >> 2;
  const int rowbase = (blockIdx.x & 3) * 128;
  const int tid  = threadIdx.x;
  const int lane = tid & 63;
  const int wv   = tid >> 6;
  const int rhalf = wv >> 2;          // 0..1 : 64-row half
  const int cpan  = wv & 3;           // 0..3 : 128-col panel
  const int l15 = lane & 15;
  const int q4  = lane >> 4;          // 0..3
  const int t0  = c * W;

  // stage initial A strip = rows [rowbase,+128) of Tb[tok0], swizzled
  {
    const ushort_t* src = Tb + (size_t)tokens[t0] * MS;
    #pragma unroll
    for (int q = 0; q < 16; ++q){
      int F = tid + q*512;
      int m = F >> 6, ch = F & 63;
      v8s val = *(const v8s*)&src[(size_t)(rowbase + m)*NSTATE + (ch ^ (m & 7))*8];
      *(v8s*)&As[m*512 + ch*8] = val;
    }
  }
  // prefetch B tile (step k=1, kk=0) into regs
  v8s breg[4];
  {
    const ushort_t* bsrc = TbT + (size_t)tokens[t0 + 1] * MS;
    #pragma unroll
    for (int q = 0; q < 4; ++q){
      int F = tid + q*512;
      int n = F >> 2, ch = F & 3;
      int s = (n + (n >> 2)) & 3;
      breg[q] = *(const v8s*)&bsrc[(size_t)n*NSTATE + (ch ^ s)*8];
    }
  }

  for (int k = 1; k < W; ++k){
    f32x4 acc[4][8];
    #pragma unroll
    for (int rt = 0; rt < 4; ++rt)
      #pragma unroll
      for (int ct = 0; ct < 8; ++ct) acc[rt][ct] = (f32x4){0.f,0.f,0.f,0.f};

    for (int kk = 0; kk < 16; ++kk){   // K in chunks of 32
      __syncthreads();                 // B readers done; A writeback visible
      #pragma unroll
      for (int q = 0; q < 4; ++q){     // commit prefetched B tile
        int F = tid + q*512;
        int n = F >> 2, ch = F & 3;
        *(v8s*)&Bs[n*32 + ch*8] = breg[q];
      }
      // prefetch next B tile (next kk, or next step's kk=0)
      {
        int nk = kk + 1, ntok = -1;
        if (nk == 16){ nk = 0; if (k + 1 < W) ntok = tokens[t0 + k + 1]; }
        else ntok = tokens[t0 + k];
        if (ntok >= 0){
          const ushort_t* bsrc = TbT + (size_t)ntok * MS;
          #pragma unroll
          for (int q = 0; q < 4; ++q){
            int F = tid + q*512;
            int n = F >> 2, ch = F & 3;
            int s = (n + (n >> 2)) & 3;
            breg[q] = *(const v8s*)&bsrc[(size_t)n*NSTATE + nk*32 + (ch ^ s)*8];
          }
        }
      }
      __syncthreads();                 // B tile visible
      v8s af[4];
      #pragma unroll
      for (int rt = 0; rt < 4; ++rt){
        int m = rhalf*64 + rt*16 + l15;
        int g = kk*4 + q4;
        af[rt] = *(const v8s*)&As[m*512 + (g ^ (m & 7))*8];
      }
      #pragma unroll
      for (int ct = 0; ct < 8; ++ct){
        int n = cpan*128 + ct*16 + l15;
        int s = (n + (n >> 2)) & 3;
        v8s b = *(const v8s*)&Bs[n*32 + (q4 ^ s)*8];
        #pragma unroll
        for (int rt = 0; rt < 4; ++rt)
          acc[rt][ct] = __builtin_amdgcn_mfma_f32_16x16x32_bf16(af[rt], b, acc[rt][ct], 0,0,0);
      }
    }
    __syncthreads();                   // all A/B reads of this step done
    if (k < W - 1){
      // write C back over the A strip (in-place, swizzled)
      #pragma unroll
      for (int rt = 0; rt < 4; ++rt){
        #pragma unroll
        for (int i = 0; i < 4; ++i){
          int mm = rhalf*64 + rt*16 + q4*4 + i;
          int swz = mm & 7;
          #pragma unroll
          for (int ct = 0; ct < 8; ++ct){
            int gcol = cpan*128 + ct*16 + l15;
            As[mm*512 + ((gcol >> 3) ^ swz)*8 + (gcol & 7)] = f2bf(acc[rt][ct][i]);
          }
        }
      }
    } else {
      // final: store to global in parity form (even chain: RM, odd: T)
      ushort_t* slot = Lout + (size_t)c * MS;
      const bool evenc = !(c & 1);
      #pragma unroll
      for (int rt = 0; rt < 4; ++rt)
        #pragma unroll
        for (int ct = 0; ct < 8; ++ct)
          #pragma unroll
          for (int i = 0; i < 4; ++i){
            int grow = rowbase + rhalf*64 + rt*16 + q4*4 + i;
            int gcol = cpan*128 + ct*16 + l15;
            ushort_t h = f2bf(acc[rt][ct][i]);
            if (evenc) slot[(size_t)grow*NSTATE + gcol] = h;
            else       slot[(size_t)gcol*NSTATE + grow] = h;
          }
    }
  }
}

// ---------------------------------------------------------------------------
// Round-3 gemm_step (32 KiB static LDS) — used by tree levels and the
// no-big-LDS fallback chain path.
// ---------------------------------------------------------------------------
__device__ __forceinline__ void gl_lds16(const void* g, void* l){
  __builtin_amdgcn_global_load_lds(
      (const __attribute__((address_space(1))) unsigned int*)g,
      (__attribute__((address_space(3))) unsigned int*)l, 16, 0, 0);
}

__device__ void gemm_step(const ushort_t* __restrict__ A,
                          const ushort_t* __restrict__ Bt,
                          ushort_t* dRM, ushort_t* dT, int rowbase){
  __shared__ __align__(16) ushort_t ldsA[128*64];
  __shared__ __align__(16) ushort_t ldsB[128*64];
  const int tid  = threadIdx.x;
  const int lane = tid & 63;
  const int w    = tid >> 6;
  const int l15  = lane & 15;
  const int koff = (lane >> 4) * 8;

  __threadfence_block();

  for (int p = 0; p < 4; ++p){
    f32x4 acc[2][8];
    #pragma unroll
    for (int rt = 0; rt < 2; ++rt)
      #pragma unroll
      for (int ct = 0; ct < 8; ++ct) acc[rt][ct] = (f32x4){0.f,0.f,0.f,0.f};

    for (int kk = 0; kk < 8; ++kk){
      __syncthreads();
      #pragma unroll
      for (int q = 0; q < 4; ++q){
        int idx = tid + q*256;
        int rr = idx >> 3, cch = idx & 7;
        gl_lds16(&A [(size_t)(rowbase + rr)*NSTATE + kk*64 + cch*8], &ldsA[idx*8]);
        gl_lds16(&Bt[(size_t)(p*128   + rr)*NSTATE + kk*64 + cch*8], &ldsB[idx*8]);
      }
      __syncthreads();
      #pragma unroll
      for (int kc = 0; kc < 2; ++kc){
        v8s a0 = *(const v8s*)&ldsA[(w*32 +      l15)*64 + kc*32 + koff];
        v8s a1 = *(const v8s*)&ldsA[(w*32 + 16 + l15)*64 + kc*32 + koff];
        #pragma unroll
        for (int ct = 0; ct < 8; ++ct){
          v8s b = *(const v8s*)&ldsB[(ct*16 + l15)*64 + kc*32 + koff];
          acc[0][ct] = __builtin_amdgcn_mfma_f32_16x16x32_bf16(a0, b, acc[0][ct], 0,0,0);
          acc[1][ct] = __builtin_amdgcn_mfma_f32_16x16x32_bf16(a1, b, acc[1][ct], 0,0,0);
        }
      }
    }
    const int rb = rowbase + w*32 + (lane >> 4)*4;
    #pragma unroll
    for (int rt = 0; rt < 2; ++rt)
      #pragma unroll
      for (int ct = 0; ct < 8; ++ct)
        #pragma unroll
        for (int i = 0; i < 4; ++i){
          int grow = rb + rt*16 + i;
          int gcol = p*128 + ct*16 + l15;
          ushort_t h = f2bf(acc[rt][ct][i]);
          if (dRM) dRM[(size_t)grow*NSTATE + gcol] = h;
          if (dT)  dT [(size_t)gcol*NSTATE + grow] = h;
        }
  }
  __syncthreads();
}

__global__ __launch_bounds__(256) void k_prep(const float* __restrict__ transfer,
                                              ushort_t* __restrict__ Tb,
                                              ushort_t* __restrict__ TbT){
  __shared__ ushort_t t[32*512];
  const int s = blockIdx.x >> 4;
  const int krows = (blockIdx.x & 15) * 32;
  const int tid = threadIdx.x;
  for (int idx = tid; idx < 32*512; idx += 256){
    int r = idx >> 9, n = idx & 511;
    ushort_t h = f2bf(transfer[(size_t)s*MS + (size_t)(krows + r)*NSTATE + n]);
    Tb[(size_t)s*MS + (size_t)(krows + r)*NSTATE + n] = h;
    t[r*512 + n] = h;
  }
  __syncthreads();
  for (int idx = tid; idx < 512*4; idx += 256){
    int n = idx >> 2, cc = idx & 3;
    v8s vv;
    #pragma unroll
    for (int jj = 0; jj < 8; ++jj) vv[jj] = (short)t[(cc*8 + jj)*512 + n];
    *(v8s*)&TbT[(size_t)s*MS + (size_t)n*NSTATE + krows + cc*8] = vv;
  }
}

// fallback chain (global ping/pong intermediates) if big-LDS unavailable
__global__ __launch_bounds__(256) void k_chain(const int* __restrict__ tokens,
    const ushort_t* __restrict__ Tb, const ushort_t* __restrict__ TbT,
    ushort_t* ping, ushort_t* pong, ushort_t* Lout, int W){
  const int c = blockIdx.x >> 2;
  const int r = blockIdx.x & 3;
  const int t0 = c * W;
  ushort_t* bufA = ping + (size_t)c * MS;
  ushort_t* bufB = pong + (size_t)c * MS;
  for (int k = 1; k < W; ++k){
    const ushort_t* Asrc = (k == 1) ? Tb + (size_t)tokens[t0] * MS
                                    : (((k - 1) & 1) ? bufA : bufB);
    ushort_t *dRM, *dT;
    if (k == W - 1){
      ushort_t* slot = Lout + (size_t)c * MS;
      dRM = (c & 1) ? nullptr : slot;
      dT  = (c & 1) ? slot    : nullptr;
    } else {
      dRM = (k & 1) ? bufA : bufB; dT = nullptr;
    }
    gemm_step(Asrc, TbT + (size_t)tokens[t0 + k] * MS, dRM, dT, r * 128);
  }
}

// One tree level: Ldst[j] = Lsrc[2j] (RM) @ Lsrc[2j+1] (T); dst parity form.
__global__ __launch_bounds__(256) void k_tree(const ushort_t* __restrict__ Lsrc,
                                              ushort_t* __restrict__ Ldst){
  const int j = blockIdx.x >> 2, r = blockIdx.x & 3;
  const ushort_t* A  = Lsrc + (size_t)(2*j)     * MS;
  const ushort_t* Bt = Lsrc + (size_t)(2*j + 1) * MS;
  ushort_t* slot = Ldst + (size_t)j * MS;
  gemm_step(A, Bt, (j & 1) ? nullptr : slot, (j & 1) ? slot : nullptr, r * 128);
}

// Boundary vectors u_g via binary decomposition over tree levels 5..11.
__global__ __launch_bounds__(512) void k_descent(const float* __restrict__ start,
    const ushort_t* __restrict__ Upper, float* __restrict__ u){
  __shared__ float v[NSTATE];
  const int base5[7] = {0,128,192,224,240,248,252};
  const int g = blockIdx.x, tid = threadIdx.x;
  v[tid] = start[tid];
  __syncthreads();
  int pos = 0;
  for (int l = 6; l >= 0; --l){
    if ((g >> l) & 1){
      const ushort_t* M = Upper + (size_t)(base5[l] + (pos >> l)) * MS;
      float a0=0.f,a1=0.f,a2=0.f,a3=0.f;
      #pragma unroll 4
      for (int i = 0; i < NSTATE; i += 4){
        a0 += v[i  ] * bf2f(M[(size_t)(i  )*NSTATE + tid]);
        a1 += v[i+1] * bf2f(M[(size_t)(i+1)*NSTATE + tid]);
        a2 += v[i+2] * bf2f(M[(size_t)(i+2)*NSTATE + tid]);
        a3 += v[i+3] * bf2f(M[(size_t)(i+3)*NSTATE + tid]);
      }
      __syncthreads();
      v[tid] = (a0+a1)+(a2+a3);
      __syncthreads();
      pos += 1 << l;
    }
  }
  u[(size_t)g*NSTATE + tid] = v[tid];
}

// Per-segment replay: 32 serial f32 vecmat steps from u_g; emission factor
// (v.p)/(sum v); g=127 emits `internal` normalized to mass 1.
__global__ __launch_bounds__(512) void k_phase2(const int* __restrict__ tokens,
    const float* __restrict__ u, const ushort_t* __restrict__ Tb,
    const float* __restrict__ probs, float* __restrict__ partials,
    float* __restrict__ out){
  __shared__ float v[NSTATE];
  __shared__ float redc[8], redm[8];
  __shared__ float fac, minv;
  const int g = blockIdx.x, tid = threadIdx.x;
  v[tid] = u[(size_t)g*NSTATE + tid];
  float pp = 1.f;
  __syncthreads();
  for (int k = 0; k < SEG; ++k){
    const int tok = tokens[g*SEG + k];
    float a = v[tid];
    float b = a * probs[(size_t)tok*NSTATE + tid];
    #pragma unroll
    for (int o = 32; o > 0; o >>= 1){
      a += __shfl_down(a, o);
      b += __shfl_down(b, o);
    }
    if ((tid & 63) == 0){ redm[tid >> 6] = a; redc[tid >> 6] = b; }
    __syncthreads();
    if (tid == 0){
      float m = 0.f, cc = 0.f;
      #pragma unroll
      for (int q = 0; q < 8; ++q){ m += redm[q]; cc += redc[q]; }
      fac = cc / m;
    }
    __syncthreads();
    pp *= fac;
    const ushort_t* M = Tb + (size_t)tok * MS;
    float a0=0.f,a1=0.f,a2=0.f,a3=0.f;
    #pragma unroll 4
    for (int i = 0; i < NSTATE; i += 4){
      a0 += v[i  ] * bf2f(M[(size_t)(i  )*NSTATE + tid]);
      a1 += v[i+1] * bf2f(M[(size_t)(i+1)*NSTATE + tid]);
      a2 += v[i+2] * bf2f(M[(size_t)(i+2)*NSTATE + tid]);
      a3 += v[i+3] * bf2f(M[(size_t)(i+3)*NSTATE + tid]);
    }
    __syncthreads();
    v[tid] = (a0+a1)+(a2+a3);
    __syncthreads();
  }
  if (tid == 0) partials[g] = pp;
  if (g == GSEG - 1){
    float a = v[tid];
    #pragma unroll
    for (int o = 32; o > 0; o >>= 1) a += __shfl_down(a, o);
    if ((tid & 63) == 0) redm[tid >> 6] = a;
    __syncthreads();
    if (tid == 0){
      float m = 0.f;
      #pragma unroll
      for (int q = 0; q < 8; ++q) m += redm[q];
      minv = 1.f / m;
    }
    __syncthreads();
    out[tid] = v[tid] * minv;
  }
}

__global__ __launch_bounds__(512) void k_finish(const float* __restrict__ partials,
    const float* __restrict__ finals, float* out){
  __shared__ float red[8];
  const int tid = threadIdx.x;
  float x = out[tid] * finals[tid];
  #pragma unroll
  for (int o = 32; o > 0; o >>= 1) x += __shfl_down(x, o);
  if ((tid & 63) == 0) red[tid >> 6] = x;
  __syncthreads();
  if (tid == 0){
    float s = 0.f;
    for (int q = 0; q < 8; ++q) s += red[q];
    float pp = 1.f;
    for (int q = 0; q < GSEG; ++q) pp *= partials[q];
    out[NSTATE] = pp * s;
  }
}

__global__ __launch_bounds__(512) void k_fallback(const int* __restrict__ tokens,
    const float* __restrict__ start, const float* __restrict__ transfer,
    const float* __restrict__ probs, const float* __restrict__ finals,
    float* out){
  __shared__ float v[NSTATE];
  __shared__ float red[9];
  const int tid = threadIdx.x;
  v[tid] = start[tid];
  float pp = 1.f;
  __syncthreads();
  for (int t = 0; t < LTOK; ++t){
    const int tok = tokens[t];
    float x = v[tid] * probs[(size_t)tok*NSTATE + tid];
    #pragma unroll
    for (int o = 32; o > 0; o >>= 1) x += __shfl_down(x, o);
    if ((tid & 63) == 0) red[tid >> 6] = x;
    __syncthreads();
    if (tid == 0){
      float cc = 0.f;
      for (int q = 0; q < 8; ++q) cc += red[q];
      red[8] = cc;
    }
    __syncthreads();
    pp *= red[8];
    const float* M = transfer + (size_t)tok * MS;
    float acc = 0.f;
    #pragma unroll 8
    for (int i = 0; i < NSTATE; ++i) acc += v[i] * M[(size_t)i*NSTATE + tid];
    __syncthreads();
    v[tid] = acc;
    __syncthreads();
  }
  out[tid] = v[tid];
  float x = v[tid] * finals[tid];
  #pragma unroll
  for (int o = 32; o > 0; o >>= 1) x += __shfl_down(x, o);
  if ((tid & 63) == 0) red[tid >> 6] = x;
  __syncthreads();
  if (tid == 0){
    float s = 0.f;
    for (int q = 0; q < 8; ++q) s += red[q];
    out[NSTATE] = pp * s;
  }
}

extern "C" void kernel_launch(void* const* d_in, const int* in_sizes, int n_in,
                              void* d_out, int out_size, void* d_ws, size_t ws_size,
                              hipStream_t stream) {
  const int*   tokens   = (const int*)  d_in[0];
  const float* start    = (const float*)d_in[1];
  const float* transfer = (const float*)d_in[2];
  const float* probs    = (const float*)d_in[3];
  const float* finals   = (const float*)d_in[4];
  float* out = (float*)d_out;
  (void)in_sizes; (void)n_in; (void)out_size;

  const size_t C2 = MS * 2;
  size_t off = 0;
  const size_t o_Tb    = off; off += C2 * NSYM;    // 64 MiB
  const size_t o_TbT   = off; off += C2 * NSYM;    // 64 MiB
  const size_t o_Upper = off; off += C2 * 254;     // 127 MiB (tree levels 5..11)
  const size_t o_u     = off; off += (size_t)GSEG * NSTATE * 4;
  const size_t o_part  = off; off += GSEG * 4 + 256;
  const size_t common  = off;                      // ~255.4 MiB

  // big-LDS opt-in (host-side, idempotent, graph-capture-safe)
  const int LDSBYTES = (128*512 + 512*32) * 2;     // 163840
  bool bigLds = hipFuncSetAttribute(
      reinterpret_cast<const void*>(k_chain_lds),
      hipFuncAttributeMaxDynamicSharedMemorySize, LDSBYTES) == hipSuccess;

  char* ws = (char*)d_ws;
  ushort_t* Tb    = (ushort_t*)(ws + o_Tb);
  ushort_t* TbT   = (ushort_t*)(ws + o_TbT);
  ushort_t* Upper = (ushort_t*)(ws + o_Upper);
  float*    u     = (float*)   (ws + o_u);
  float*    parts = (float*)   (ws + o_part);

  const int upOff[7] = {0,128,192,224,240,248,252};
  ushort_t* lvl[12] = {nullptr};
  for (int l = 5; l <= 11; ++l) lvl[l] = Upper + (size_t)upOff[l-5] * MS;

  int W = 0, sLvl = 0;
  size_t oo = common;
  if (bigLds){
    // no ping/pong needed; only sub-level-5 tree buffers
    if      (ws_size >= common + C2 * (512 + 256)) { W = 8;  sLvl = 3; }
    else if (ws_size >= common + C2 * 256)         { W = 16; sLvl = 4; }
    else if (ws_size >= common)                    { W = 32; sLvl = 5; }
    if (W){
      if (W == 8){ lvl[3] = (ushort_t*)(ws + oo); oo += C2 * 512; }
      if (W <= 16){ lvl[4] = (ushort_t*)(ws + oo); oo += C2 * 256; }
    }
  } else {
    // round-3 path: needs ping/pong for W=32 (128+128 mats)
    if (ws_size >= common + C2 * 256) { W = 32; sLvl = 5; }
  }
  if (!W){
    k_fallback<<<1, 512, 0, stream>>>(tokens, start, transfer, probs, finals, out);
    return;
  }
  const int nchain = LTOK / W;

  k_prep<<<NSYM * 16, 256, 0, stream>>>(transfer, Tb, TbT);
  if (bigLds){
    k_chain_lds<<<nchain * 4, 512, LDSBYTES, stream>>>(tokens, Tb, TbT, lvl[sLvl], W);
  } else {
    ushort_t* ping = (ushort_t*)(ws + oo); oo += C2 * nchain;
    ushort_t* pong = (ushort_t*)(ws + oo); oo += C2 * nchain;
    k_chain<<<nchain * 4, 256, 0, stream>>>(tokens, Tb, TbT, ping, pong, lvl[sLvl], W);
  }
  for (int l = sLvl; l < 11; ++l){
    const int cntNext = LTOK >> (l + 1);
    k_tree<<<cntNext * 4, 256, 0, stream>>>(lvl[l], lvl[l + 1]);
  }
  k_descent<<<GSEG, 512, 0, stream>>>(start, Upper, u);
  k_phase2 <<<GSEG, 512, 0, stream>>>(tokens, u, Tb, probs, parts, out);
  k_finish <<<1,    512, 0, stream>>>(parts, finals, out);
}

// Round 5
// 2805.600 us; speedup vs baseline: 2.0881x; 1.7030x over previous
//
#include <hip/hip_runtime.h>
#include <stdint.h>

// AutomatonNetwork: 4096-step vecmat chain lifted to a bf16 MFMA product tree.
// Round-5: operand-role-swapped LDS-resident chains (Ct = Btok^T * Strip^T):
//  * strip stays the MFMA B-operand -> writeback is native row-major b64
//    (32 ds_write_b64/thread/step instead of 128 ds_write_b16 scatter)
//  * XCD-affine swizzle: a chain's 4 strips concurrent on one XCD -> token
//    tile fetched ~once per chain into L2 (round-4 fetched it 4x from HBM)
//  * depth-2 register prefetch of token tiles; stronger XOR bank swizzles
//  * phase2/descent at G=256 segments (SEG=16) using level-4 tree nodes
// Numerics: emission factors (v.p)/(sum v) cancel bf16 mass drift (proven,
// absmax 1.5e-5 vs 4e-3 threshold across rounds 2-4).

typedef unsigned short ushort_t;
typedef __attribute__((ext_vector_type(8))) short v8s;    // 8 bf16 MFMA frag
typedef __attribute__((ext_vector_type(4))) float f32x4;  // MFMA 16x16 acc

#define NSTATE 512
#define NSYM   128
#define LTOK   4096
#define MS     ((size_t)NSTATE*NSTATE)

__device__ __forceinline__ ushort_t f2bf(float f){
  unsigned u = __float_as_uint(f);
  u = u + 0x7FFFu + ((u >> 16) & 1u);    // RNE
  return (ushort_t)(u >> 16);
}
__device__ __forceinline__ float bf2f(ushort_t h){
  return __uint_as_float(((unsigned)h) << 16);
}

// ---------------------------------------------------------------------------
// LDS-resident chain, role-swapped. WG (c, r) owns strip = rows [128r,+128)
// of chain c's running product, held in LDS (128 KiB) for all W-1 steps.
// We compute D = Ct = Btok^T(512x512, K=512) * Strip^T(512x128):
//   A-frag (m'=token col): TbT[m'*512+k] contiguous (staged 512x32/kk)
//   B-frag (n=strip row):  As[n*512+k]  contiguous
//   D: lane l15 -> strip row (col of Ct); q4*4+i -> consecutive C cols
// 512 thr = 8 waves; wave wv owns C cols [64wv,+64); acc 4x8 f32x4 = 128/lane.
// Swizzles (chunk = 16B): As: p holds true chunk p^(m&7); Ts: p^((m>>1)&3).
// mfma_f32_16x16x32_bf16 layouts HW-verified (rounds 2-4 end-to-end).
// ---------------------------------------------------------------------------
#define ISSUE(tt, R) do { int _t = (tt); if (_t < T){                         \
    int _k = 1 + (_t >> 4), _kk = _t & 15;                                    \
    const ushort_t* _bs = TbT + (size_t)tokens[t0 + _k] * MS;                 \
    _Pragma("unroll") for (int q = 0; q < 4; ++q){                            \
      int F = tid + q*512; int m = F >> 2, p = F & 3;                         \
      R[q] = *(const v8s*)&_bs[(size_t)m*NSTATE + _kk*32 + ((p ^ ((m>>1)&3))*8)]; \
    } } } while(0)

#define COMMIT(R) do { _Pragma("unroll") for (int q = 0; q < 4; ++q){         \
    int F = tid + q*512; int m = F >> 2, p = F & 3;                           \
    *(v8s*)&Ts[m*32 + p*8] = R[q]; } } while(0)

__global__ __launch_bounds__(512, 2) void k_chain_lds(
    const int* __restrict__ tokens, const ushort_t* __restrict__ Tb,
    const ushort_t* __restrict__ TbT, ushort_t* __restrict__ Lout, int W){
  extern __shared__ __align__(16) ushort_t lds[];
  ushort_t* As = lds;                  // 128x512 strip, row-major, swizzled
  ushort_t* Ts = lds + 128*512;        // 512x32 token K-slice, swizzled
  const int b = blockIdx.x;
  const int c       = (b >> 5) * 8 + (b & 7);   // chain (XCD-affine)
  const int rowbase = ((b >> 3) & 3) * 128;     // strip rows
  const int tid  = threadIdx.x;
  const int lane = tid & 63;
  const int wv   = tid >> 6;           // 0..7 : 64-wide C-col panel
  const int l15  = lane & 15;
  const int q4   = lane >> 4;
  const int t0   = c * W;
  const int T    = (W - 1) * 16;

  // stage initial strip = rows [rowbase,+128) of Tb[tok0] (swizzled store)
  {
    const ushort_t* src = Tb + (size_t)tokens[t0] * MS;
    #pragma unroll
    for (int q = 0; q < 16; ++q){
      int F = tid + q*512;
      int m = F >> 6, p = F & 63;
      *(v8s*)&As[m*512 + p*8] =
        *(const v8s*)&src[(size_t)(rowbase + m)*NSTATE + ((p ^ (m & 7))*8)];
    }
  }

  v8s tregA[4], tregB[4];
  ISSUE(0, tregA);
  ISSUE(1, tregB);

  for (int k = 1; k < W; ++k){
    f32x4 acc[4][8];
    #pragma unroll
    for (int mt = 0; mt < 4; ++mt)
      #pragma unroll
      for (int nt = 0; nt < 8; ++nt) acc[mt][nt] = (f32x4){0.f,0.f,0.f,0.f};

    const int tb = (k - 1) * 16;
    #pragma unroll
    for (int kk2 = 0; kk2 < 16; kk2 += 2){
      #pragma unroll
      for (int sub = 0; sub < 2; ++sub){
        const int kk = kk2 + sub;
        __syncthreads();               // prior kk's Ts reads done
        if (sub == 0){ COMMIT(tregA); ISSUE(tb + kk + 2, tregA); }
        else         { COMMIT(tregB); ISSUE(tb + kk + 2, tregB); }
        __syncthreads();               // Ts visible
        v8s a[4];
        #pragma unroll
        for (int mt = 0; mt < 4; ++mt){
          int m = wv*64 + mt*16 + l15;
          a[mt] = *(const v8s*)&Ts[m*32 + ((q4 ^ ((m >> 1) & 3))*8)];
        }
        #pragma unroll
        for (int nt = 0; nt < 8; ++nt){
          int n  = nt*16 + l15;
          int ch = kk*4 + q4;
          v8s bf = *(const v8s*)&As[n*512 + ((ch ^ (n & 7))*8)];
          #pragma unroll
          for (int mt = 0; mt < 4; ++mt)
            acc[mt][nt] = __builtin_amdgcn_mfma_f32_16x16x32_bf16(a[mt], bf, acc[mt][nt], 0,0,0);
        }
      }
    }
    __syncthreads();                   // all As/Ts reads of this step done
    if (k < W - 1){
      // native row-major writeback: lane holds 4 consecutive C cols per acc
      #pragma unroll
      for (int nt = 0; nt < 8; ++nt){
        int n = nt*16 + l15;
        #pragma unroll
        for (int mt = 0; mt < 4; ++mt){
          int col = wv*64 + mt*16 + q4*4;
          ushort4 h;
          h.x = f2bf(acc[mt][nt][0]); h.y = f2bf(acc[mt][nt][1]);
          h.z = f2bf(acc[mt][nt][2]); h.w = f2bf(acc[mt][nt][3]);
          int p = (col >> 3) ^ (n & 7);
          *(ushort4*)&As[n*512 + p*8 + (col & 7)] = h;
        }
      }
    } else {
      ushort_t* slot = Lout + (size_t)c * MS;
      if (!(c & 1)){
        // even chain: row-major global store, b64 coalesced-ish
        #pragma unroll
        for (int nt = 0; nt < 8; ++nt){
          int grow = rowbase + nt*16 + l15;
          #pragma unroll
          for (int mt = 0; mt < 4; ++mt){
            int gcol = wv*64 + mt*16 + q4*4;
            ushort4 h;
            h.x = f2bf(acc[mt][nt][0]); h.y = f2bf(acc[mt][nt][1]);
            h.z = f2bf(acc[mt][nt][2]); h.w = f2bf(acc[mt][nt][3]);
            *(ushort4*)&slot[(size_t)grow*NSTATE + gcol] = h;
          }
        }
      } else {
        // odd chain: transposed store via verified 4x4 quad butterfly
        #pragma unroll
        for (int nt = 0; nt < 8; ++nt){
          int growb = rowbase + nt*16 + (l15 & 12);
          #pragma unroll
          for (int mt = 0; mt < 4; ++mt){
            float v0 = acc[mt][nt][0], v1 = acc[mt][nt][1];
            float v2 = acc[mt][nt][2], v3 = acc[mt][nt][3];
            float s0 = __shfl_xor(v0, 2), s1 = __shfl_xor(v1, 2);
            float s2 = __shfl_xor(v2, 2), s3 = __shfl_xor(v3, 2);
            const bool h2 = lane & 2;
            float c0 = h2 ? s2 : v0, c1 = h2 ? s3 : v1;
            float c2 = h2 ? v2 : s0, c3 = h2 ? v3 : s1;
            float u0 = __shfl_xor(c0, 1), u1 = __shfl_xor(c1, 1);
            float u2 = __shfl_xor(c2, 1), u3 = __shfl_xor(c3, 1);
            const bool h1 = lane & 1;
            float d0 = h1 ? u1 : c0, d1 = h1 ? c1 : u0;
            float d2 = h1 ? u3 : c2, d3 = h1 ? c3 : u2;
            int gcol = wv*64 + mt*16 + q4*4 + (lane & 3);
            ushort4 h;
            h.x = f2bf(d0); h.y = f2bf(d1); h.z = f2bf(d2); h.w = f2bf(d3);
            *(ushort4*)&slot[(size_t)gcol*NSTATE + growb] = h;
          }
        }
      }
    }
  }
}

// ---------------------------------------------------------------------------
// Round-3 gemm_step (32 KiB static LDS) — tree levels + no-big-LDS fallback.
// ---------------------------------------------------------------------------
__device__ __forceinline__ void gl_lds16(const void* g, void* l){
  __builtin_amdgcn_global_load_lds(
      (const __attribute__((address_space(1))) unsigned int*)g,
      (__attribute__((address_space(3))) unsigned int*)l, 16, 0, 0);
}

__device__ void gemm_step(const ushort_t* __restrict__ A,
                          const ushort_t* __restrict__ Bt,
                          ushort_t* dRM, ushort_t* dT, int rowbase){
  __shared__ __align__(16) ushort_t ldsA[128*64];
  __shared__ __align__(16) ushort_t ldsB[128*64];
  const int tid  = threadIdx.x;
  const int lane = tid & 63;
  const int w    = tid >> 6;
  const int l15  = lane & 15;
  const int koff = (lane >> 4) * 8;

  __threadfence_block();

  for (int p = 0; p < 4; ++p){
    f32x4 acc[2][8];
    #pragma unroll
    for (int rt = 0; rt < 2; ++rt)
      #pragma unroll
      for (int ct = 0; ct < 8; ++ct) acc[rt][ct] = (f32x4){0.f,0.f,0.f,0.f};

    for (int kk = 0; kk < 8; ++kk){
      __syncthreads();
      #pragma unroll
      for (int q = 0; q < 4; ++q){
        int idx = tid + q*256;
        int rr = idx >> 3, cch = idx & 7;
        gl_lds16(&A [(size_t)(rowbase + rr)*NSTATE + kk*64 + cch*8], &ldsA[idx*8]);
        gl_lds16(&Bt[(size_t)(p*128   + rr)*NSTATE + kk*64 + cch*8], &ldsB[idx*8]);
      }
      __syncthreads();
      #pragma unroll
      for (int kc = 0; kc < 2; ++kc){
        v8s a0 = *(const v8s*)&ldsA[(w*32 +      l15)*64 + kc*32 + koff];
        v8s a1 = *(const v8s*)&ldsA[(w*32 + 16 + l15)*64 + kc*32 + koff];
        #pragma unroll
        for (int ct = 0; ct < 8; ++ct){
          v8s bb = *(const v8s*)&ldsB[(ct*16 + l15)*64 + kc*32 + koff];
          acc[0][ct] = __builtin_amdgcn_mfma_f32_16x16x32_bf16(a0, bb, acc[0][ct], 0,0,0);
          acc[1][ct] = __builtin_amdgcn_mfma_f32_16x16x32_bf16(a1, bb, acc[1][ct], 0,0,0);
        }
      }
    }
    const int rb = rowbase + w*32 + (lane >> 4)*4;
    #pragma unroll
    for (int rt = 0; rt < 2; ++rt)
      #pragma unroll
      for (int ct = 0; ct < 8; ++ct)
        #pragma unroll
        for (int i = 0; i < 4; ++i){
          int grow = rb + rt*16 + i;
          int gcol = p*128 + ct*16 + l15;
          ushort_t h = f2bf(acc[rt][ct][i]);
          if (dRM) dRM[(size_t)grow*NSTATE + gcol] = h;
          if (dT)  dT [(size_t)gcol*NSTATE + grow] = h;
        }
  }
  __syncthreads();
}

__global__ __launch_bounds__(256) void k_prep(const float* __restrict__ transfer,
                                              ushort_t* __restrict__ Tb,
                                              ushort_t* __restrict__ TbT){
  __shared__ ushort_t t[32*512];
  const int s = blockIdx.x >> 4;
  const int krows = (blockIdx.x & 15) * 32;
  const int tid = threadIdx.x;
  for (int idx = tid; idx < 32*512; idx += 256){
    int r = idx >> 9, n = idx & 511;
    ushort_t h = f2bf(transfer[(size_t)s*MS + (size_t)(krows + r)*NSTATE + n]);
    Tb[(size_t)s*MS + (size_t)(krows + r)*NSTATE + n] = h;
    t[r*512 + n] = h;
  }
  __syncthreads();
  for (int idx = tid; idx < 512*4; idx += 256){
    int n = idx >> 2, cc = idx & 3;
    v8s vv;
    #pragma unroll
    for (int jj = 0; jj < 8; ++jj) vv[jj] = (short)t[(cc*8 + jj)*512 + n];
    *(v8s*)&TbT[(size_t)s*MS + (size_t)n*NSTATE + krows + cc*8] = vv;
  }
}

// fallback chain (global ping/pong intermediates) if big-LDS unavailable
__global__ __launch_bounds__(256) void k_chain(const int* __restrict__ tokens,
    const ushort_t* __restrict__ Tb, const ushort_t* __restrict__ TbT,
    ushort_t* ping, ushort_t* pong, ushort_t* Lout, int W){
  const int c = blockIdx.x >> 2;
  const int r = blockIdx.x & 3;
  const int t0 = c * W;
  ushort_t* bufA = ping + (size_t)c * MS;
  ushort_t* bufB = pong + (size_t)c * MS;
  for (int k = 1; k < W; ++k){
    const ushort_t* Asrc = (k == 1) ? Tb + (size_t)tokens[t0] * MS
                                    : (((k - 1) & 1) ? bufA : bufB);
    ushort_t *dRM, *dT;
    if (k == W - 1){
      ushort_t* slot = Lout + (size_t)c * MS;
      dRM = (c & 1) ? nullptr : slot;
      dT  = (c & 1) ? slot    : nullptr;
    } else {
      dRM = (k & 1) ? bufA : bufB; dT = nullptr;
    }
    gemm_step(Asrc, TbT + (size_t)tokens[t0 + k] * MS, dRM, dT, r * 128);
  }
}

__global__ __launch_bounds__(256) void k_tree(const ushort_t* __restrict__ Lsrc,
                                              ushort_t* __restrict__ Ldst){
  const int j = blockIdx.x >> 2, r = blockIdx.x & 3;
  const ushort_t* A  = Lsrc + (size_t)(2*j)     * MS;
  const ushort_t* Bt = Lsrc + (size_t)(2*j + 1) * MS;
  ushort_t* slot = Ldst + (size_t)j * MS;
  gemm_step(A, Bt, (j & 1) ? nullptr : slot, (j & 1) ? slot : nullptr, r * 128);
}

// Boundary vectors u_g via binary decomposition over tree levels baseLvl..11.
// Node index (pos>>p) always even -> RM form available.
__global__ __launch_bounds__(512) void k_descent(const float* __restrict__ start,
    const ushort_t* __restrict__ lvl4, const ushort_t* __restrict__ Upper,
    float* __restrict__ u, int baseLvl){
  __shared__ float v[NSTATE];
  const int upOff[7] = {0,128,192,224,240,248,252};  // levels 5..11 in Upper
  const int g = blockIdx.x, tid = threadIdx.x;
  v[tid] = start[tid];
  __syncthreads();
  int pos = 0;
  for (int p = 11 - baseLvl; p >= 0; --p){
    if ((g >> p) & 1){
      const int L = baseLvl + p;
      const ushort_t* arr = (L == 4) ? lvl4 : (Upper + (size_t)upOff[L-5] * MS);
      const ushort_t* M = arr + (size_t)(pos >> p) * MS;
      float a0=0.f,a1=0.f,a2=0.f,a3=0.f;
      #pragma unroll 4
      for (int i = 0; i < NSTATE; i += 4){
        a0 += v[i  ] * bf2f(M[(size_t)(i  )*NSTATE + tid]);
        a1 += v[i+1] * bf2f(M[(size_t)(i+1)*NSTATE + tid]);
        a2 += v[i+2] * bf2f(M[(size_t)(i+2)*NSTATE + tid]);
        a3 += v[i+3] * bf2f(M[(size_t)(i+3)*NSTATE + tid]);
      }
      __syncthreads();
      v[tid] = (a0+a1)+(a2+a3);
      __syncthreads();
      pos += 1 << p;
    }
  }
  u[(size_t)g*NSTATE + tid] = v[tid];
}

// Per-segment replay: SEG serial f32 vecmat steps from u_g; emission factor
// (v.p)/(sum v); last segment emits `internal` normalized to mass 1.
__global__ __launch_bounds__(512) void k_phase2(const int* __restrict__ tokens,
    const float* __restrict__ u, const ushort_t* __restrict__ Tb,
    const float* __restrict__ probs, float* __restrict__ partials,
    float* __restrict__ out, int SEG){
  __shared__ float v[NSTATE];
  __shared__ float redc[8], redm[8];
  __shared__ float fac, minv;
  const int g = blockIdx.x, tid = threadIdx.x;
  v[tid] = u[(size_t)g*NSTATE + tid];
  float pp = 1.f;
  __syncthreads();
  for (int k = 0; k < SEG; ++k){
    const int tok = tokens[g*SEG + k];
    float a = v[tid];
    float bb = a * probs[(size_t)tok*NSTATE + tid];
    #pragma unroll
    for (int o = 32; o > 0; o >>= 1){
      a  += __shfl_down(a, o);
      bb += __shfl_down(bb, o);
    }
    if ((tid & 63) == 0){ redm[tid >> 6] = a; redc[tid >> 6] = bb; }
    __syncthreads();
    if (tid == 0){
      float m = 0.f, cc = 0.f;
      #pragma unroll
      for (int q = 0; q < 8; ++q){ m += redm[q]; cc += redc[q]; }
      fac = cc / m;
    }
    __syncthreads();
    pp *= fac;
    const ushort_t* M = Tb + (size_t)tok * MS;
    float a0=0.f,a1=0.f,a2=0.f,a3=0.f;
    #pragma unroll 4
    for (int i = 0; i < NSTATE; i += 4){
      a0 += v[i  ] * bf2f(M[(size_t)(i  )*NSTATE + tid]);
      a1 += v[i+1] * bf2f(M[(size_t)(i+1)*NSTATE + tid]);
      a2 += v[i+2] * bf2f(M[(size_t)(i+2)*NSTATE + tid]);
      a3 += v[i+3] * bf2f(M[(size_t)(i+3)*NSTATE + tid]);
    }
    __syncthreads();
    v[tid] = (a0+a1)+(a2+a3);
    __syncthreads();
  }
  if (tid == 0) partials[g] = pp;
  if (g == gridDim.x - 1){
    float a = v[tid];
    #pragma unroll
    for (int o = 32; o > 0; o >>= 1) a += __shfl_down(a, o);
    if ((tid & 63) == 0) redm[tid >> 6] = a;
    __syncthreads();
    if (tid == 0){
      float m = 0.f;
      #pragma unroll
      for (int q = 0; q < 8; ++q) m += redm[q];
      minv = 1.f / m;
    }
    __syncthreads();
    out[tid] = v[tid] * minv;
  }
}

__global__ __launch_bounds__(512) void k_finish(const float* __restrict__ partials,
    const float* __restrict__ finals, float* out, int G){
  __shared__ float red[8];
  const int tid = threadIdx.x;
  float x = out[tid] * finals[tid];
  #pragma unroll
  for (int o = 32; o > 0; o >>= 1) x += __shfl_down(x, o);
  if ((tid & 63) == 0) red[tid >> 6] = x;
  __syncthreads();
  if (tid == 0){
    float s = 0.f;
    for (int q = 0; q < 8; ++q) s += red[q];
    float pp = 1.f;
    for (int q = 0; q < G; ++q) pp *= partials[q];
    out[NSTATE] = pp * s;
  }
}

__global__ __launch_bounds__(512) void k_fallback(const int* __restrict__ tokens,
    const float* __restrict__ start, const float* __restrict__ transfer,
    const float* __restrict__ probs, const float* __restrict__ finals,
    float* out){
  __shared__ float v[NSTATE];
  __shared__ float red[9];
  const int tid = threadIdx.x;
  v[tid] = start[tid];
  float pp = 1.f;
  __syncthreads();
  for (int t = 0; t < LTOK; ++t){
    const int tok = tokens[t];
    float x = v[tid] * probs[(size_t)tok*NSTATE + tid];
    #pragma unroll
    for (int o = 32; o > 0; o >>= 1) x += __shfl_down(x, o);
    if ((tid & 63) == 0) red[tid >> 6] = x;
    __syncthreads();
    if (tid == 0){
      float cc = 0.f;
      for (int q = 0; q < 8; ++q) cc += red[q];
      red[8] = cc;
    }
    __syncthreads();
    pp *= red[8];
    const float* M = transfer + (size_t)tok * MS;
    float acc = 0.f;
    #pragma unroll 8
    for (int i = 0; i < NSTATE; ++i) acc += v[i] * M[(size_t)i*NSTATE + tid];
    __syncthreads();
    v[tid] = acc;
    __syncthreads();
  }
  out[tid] = v[tid];
  float x = v[tid] * finals[tid];
  #pragma unroll
  for (int o = 32; o > 0; o >>= 1) x += __shfl_down(x, o);
  if ((tid & 63) == 0) red[tid >> 6] = x;
  __syncthreads();
  if (tid == 0){
    float s = 0.f;
    for (int q = 0; q < 8; ++q) s += red[q];
    out[NSTATE] = pp * s;
  }
}

extern "C" void kernel_launch(void* const* d_in, const int* in_sizes, int n_in,
                              void* d_out, int out_size, void* d_ws, size_t ws_size,
                              hipStream_t stream) {
  const int*   tokens   = (const int*)  d_in[0];
  const float* start    = (const float*)d_in[1];
  const float* transfer = (const float*)d_in[2];
  const float* probs    = (const float*)d_in[3];
  const float* finals   = (const float*)d_in[4];
  float* out = (float*)d_out;
  (void)in_sizes; (void)n_in; (void)out_size;

  const size_t C2 = MS * 2;
  size_t off = 0;
  const size_t o_Tb    = off; off += C2 * NSYM;    // 64 MiB
  const size_t o_TbT   = off; off += C2 * NSYM;    // 64 MiB
  const size_t o_Upper = off; off += C2 * 254;     // 127 MiB (tree levels 5..11)
  const size_t o_u     = off; off += (size_t)256 * NSTATE * 4;
  const size_t o_part  = off; off += 256 * 4 + 256;
  const size_t common  = off;                      // ~255.4 MiB

  const int LDSBYTES = (128*512 + 512*32) * 2;     // 163840
  bool bigLds = hipFuncSetAttribute(
      reinterpret_cast<const void*>(k_chain_lds),
      hipFuncAttributeMaxDynamicSharedMemorySize, LDSBYTES) == hipSuccess;

  char* ws = (char*)d_ws;
  ushort_t* Tb    = (ushort_t*)(ws + o_Tb);
  ushort_t* TbT   = (ushort_t*)(ws + o_TbT);
  ushort_t* Upper = (ushort_t*)(ws + o_Upper);
  float*    u     = (float*)   (ws + o_u);
  float*    parts = (float*)   (ws + o_part);

  const int upOff[7] = {0,128,192,224,240,248,252};
  ushort_t* lvl[12] = {nullptr};
  for (int l = 5; l <= 11; ++l) lvl[l] = Upper + (size_t)upOff[l-5] * MS;

  int W = 0, sLvl = 0;
  size_t oo = common;
  if (bigLds){
    if      (ws_size >= common + C2 * (512 + 256)) { W = 8;  sLvl = 3; }
    else if (ws_size >= common + C2 * 256)         { W = 16; sLvl = 4; }
    else if (ws_size >= common)                    { W = 32; sLvl = 5; }
    if (W){
      if (W == 8) { lvl[3] = (ushort_t*)(ws + oo); oo += C2 * 512; }
      if (W <= 16){ lvl[4] = (ushort_t*)(ws + oo); oo += C2 * 256; }
    }
  } else {
    if (ws_size >= common + C2 * 256) { W = 32; sLvl = 5; }
  }
  if (!W){
    k_fallback<<<1, 512, 0, stream>>>(tokens, start, transfer, probs, finals, out);
    return;
  }
  const int nchain = LTOK / W;
  // segment granularity for the replay: 16 if level-4 nodes exist, else 32
  const int G    = lvl[4] ? 256 : 128;
  const int SEGc = LTOK / G;
  const int baseLvl = lvl[4] ? 4 : 5;

  k_prep<<<NSYM * 16, 256, 0, stream>>>(transfer, Tb, TbT);
  if (bigLds){
    k_chain_lds<<<nchain * 4, 512, LDSBYTES, stream>>>(tokens, Tb, TbT, lvl[sLvl], W);
  } else {
    ushort_t* ping = (ushort_t*)(ws + oo); oo += C2 * nchain;
    ushort_t* pong = (ushort_t*)(ws + oo); oo += C2 * nchain;
    k_chain<<<nchain * 4, 256, 0, stream>>>(tokens, Tb, TbT, ping, pong, lvl[sLvl], W);
  }
  for (int l = sLvl; l < 11; ++l){
    const int cntNext = LTOK >> (l + 1);
    k_tree<<<cntNext * 4, 256, 0, stream>>>(lvl[l], lvl[l + 1]);
  }
  k_descent<<<G, 512, 0, stream>>>(start, lvl[4], Upper, u, baseLvl);
  k_phase2 <<<G, 512, 0, stream>>>(tokens, u, Tb, probs, parts, out, SEGc);
  k_finish <<<1, 512, 0, stream>>>(parts, finals, out, G);
}

// Round 6
// 1866.872 us; speedup vs baseline: 3.1381x; 1.5028x over previous
//
#include <hip/hip_runtime.h>
#include <stdint.h>

// AutomatonNetwork: 4096-step vecmat chain lifted to a bf16 MFMA product tree.
// Round-6: barrier-free K-loop. Token/odd-node matrices are stored
// FRAGMENT-MAJOR (Tf): one wave's MFMA A-fragment = one contiguous coalesced
// 1 KiB global load -> no LDS staging, no per-kk barriers (2 per step, not 32),
// no Ts bank conflicts. Strip (running product) stays LDS-resident (128 KiB),
// read as B-fragments (2-way conflicts only = free). Tree levels reuse the
// same engine. Even nodes: row-major (descent reads these); odd nodes:
// fragment-major transposed (next level's A-operand).
// Numerics: emission factors (v.p)/(sum v) cancel bf16 mass drift (proven,
// absmax 1.5e-5 vs 4e-3 threshold, rounds 2-5).

typedef unsigned short ushort_t;
typedef __attribute__((ext_vector_type(8))) short v8s;    // 8 bf16 MFMA frag
typedef __attribute__((ext_vector_type(4))) float f32x4;  // MFMA 16x16 acc

#define NSTATE 512
#define NSYM   128
#define LTOK   4096
#define MS     ((size_t)NSTATE*NSTATE)

__device__ __forceinline__ ushort_t f2bf(float f){
  unsigned u = __float_as_uint(f);
  u = u + 0x7FFFu + ((u >> 16) & 1u);    // RNE
  return (ushort_t)(u >> 16);
}
__device__ __forceinline__ float bf2f(ushort_t h){
  return __uint_as_float(((unsigned)h) << 16);
}
// fragment-major layout: element (m, k) of M^T (i.e. M[k][m]) at:
__device__ __forceinline__ size_t fragT_idx(int m, int k){
  return ((size_t)((k >> 5)*512 + m)*4 + ((k >> 3) & 3))*8 + (k & 7);
}

// ---------------------------------------------------------------------------
// Core step: acc[mt][nt] += (M_B in fragT form) x (strip in LDS).
// D = B^T(512x512) * Strip^T: A-frag lane(m'=l15,k=q4*8+j) read DIRECTLY from
// global fragT (contiguous 1 KiB per wave load); B-frag = strip row n
// contiguous-K from LDS (chunk xor n&7). acc[mt][nt][i] = newstrip[row n =
// nt*16+l15][col = wv*64+mt*16+q4*4+i].  (layouts HW-proven rounds 2-5)
// ---------------------------------------------------------------------------
__device__ __forceinline__ void step_mfma(f32x4 acc[4][8],
    const ushort_t* __restrict__ As, const ushort_t* __restrict__ Bf,
    int wv, int l15, int q4){
  const ushort_t* base = Bf + ((size_t)(wv*64 + l15)*4 + q4)*8;
  v8s aA[4], aN[4];
  #pragma unroll
  for (int mt = 0; mt < 4; ++mt) aA[mt] = *(const v8s*)&base[mt*512];
  #pragma unroll
  for (int kk = 0; kk < 16; ++kk){
    if (kk < 15){
      #pragma unroll
      for (int mt = 0; mt < 4; ++mt)
        aN[mt] = *(const v8s*)&base[(size_t)(kk+1)*16384 + mt*512];
    }
    #pragma unroll
    for (int nt = 0; nt < 8; ++nt){
      int n  = nt*16 + l15;
      int ch = kk*4 + q4;
      v8s bf = *(const v8s*)&As[n*512 + ((ch ^ (n & 7))*8)];
      #pragma unroll
      for (int mt = 0; mt < 4; ++mt)
        acc[mt][nt] = __builtin_amdgcn_mfma_f32_16x16x32_bf16(aA[mt], bf, acc[mt][nt], 0,0,0);
    }
    #pragma unroll
    for (int mt = 0; mt < 4; ++mt) aA[mt] = aN[mt];
  }
}

// stage strip rows [rowbase,+128) of a row-major matrix into LDS (swizzled)
__device__ __forceinline__ void load_strip(ushort_t* As,
    const ushort_t* __restrict__ src, int rowbase, int tid){
  #pragma unroll
  for (int q = 0; q < 16; ++q){
    int F = tid + q*512;
    int m = F >> 6, p = F & 63;
    *(v8s*)&As[m*512 + p*8] =
      *(const v8s*)&src[(size_t)(rowbase + m)*NSTATE + ((p ^ (m & 7))*8)];
  }
}

// writeback acc over the LDS strip (in-place, swizzled, b64, 2-way free)
__device__ __forceinline__ void writeback_lds(ushort_t* As, f32x4 acc[4][8],
    int wv, int l15, int q4){
  #pragma unroll
  for (int nt = 0; nt < 8; ++nt){
    int n = nt*16 + l15;
    #pragma unroll
    for (int mt = 0; mt < 4; ++mt){
      int col = wv*64 + mt*16 + q4*4;
      ushort4 h;
      h.x = f2bf(acc[mt][nt][0]); h.y = f2bf(acc[mt][nt][1]);
      h.z = f2bf(acc[mt][nt][2]); h.w = f2bf(acc[mt][nt][3]);
      int p = (col >> 3) ^ (n & 7);
      *(ushort4*)&As[n*512 + p*8 + (col & 7)] = h;
    }
  }
}

// final store: even -> row-major; odd -> fragment-major transposed
__device__ __forceinline__ void store_out(ushort_t* slot, f32x4 acc[4][8],
    int rowbase, bool even, int lane, int wv, int l15, int q4){
  if (even){
    #pragma unroll
    for (int nt = 0; nt < 8; ++nt){
      int grow = rowbase + nt*16 + l15;
      #pragma unroll
      for (int mt = 0; mt < 4; ++mt){
        int gcol = wv*64 + mt*16 + q4*4;
        ushort4 h;
        h.x = f2bf(acc[mt][nt][0]); h.y = f2bf(acc[mt][nt][1]);
        h.z = f2bf(acc[mt][nt][2]); h.w = f2bf(acc[mt][nt][3]);
        *(ushort4*)&slot[(size_t)grow*NSTATE + gcol] = h;
      }
    }
  } else {
    // 4x4 quad butterfly (HW-proven round 5): lane ends with
    // d[i] = C[G0+i][mcol], stored contiguously in fragT (k = G0..G0+3)
    #pragma unroll
    for (int nt = 0; nt < 8; ++nt){
      int G0 = rowbase + nt*16 + (l15 & 12);
      #pragma unroll
      for (int mt = 0; mt < 4; ++mt){
        float v0 = acc[mt][nt][0], v1 = acc[mt][nt][1];
        float v2 = acc[mt][nt][2], v3 = acc[mt][nt][3];
        float s0 = __shfl_xor(v0, 2), s1 = __shfl_xor(v1, 2);
        float s2 = __shfl_xor(v2, 2), s3 = __shfl_xor(v3, 2);
        const bool h2 = lane & 2;
        float c0 = h2 ? s2 : v0, c1 = h2 ? s3 : v1;
        float c2 = h2 ? v2 : s0, c3 = h2 ? v3 : s1;
        float u0 = __shfl_xor(c0, 1), u1 = __shfl_xor(c1, 1);
        float u2 = __shfl_xor(c2, 1), u3 = __shfl_xor(c3, 1);
        const bool h1 = lane & 1;
        float d0 = h1 ? u1 : c0, d1 = h1 ? c1 : u0;
        float d2 = h1 ? u3 : c2, d3 = h1 ? c3 : u2;
        int mcol = wv*64 + mt*16 + q4*4 + (lane & 3);
        ushort4 h;
        h.x = f2bf(d0); h.y = f2bf(d1); h.z = f2bf(d2); h.w = f2bf(d3);
        *(ushort4*)&slot[fragT_idx(mcol, G0)] = h;
      }
    }
  }
}

// Chains: WG (c, r) holds strip rows [128r,+128) of chain c in LDS across
// all W-1 steps; token B-matrices consumed straight from global fragT.
__global__ __launch_bounds__(512, 2) void k_chain2(
    const int* __restrict__ tokens, const ushort_t* __restrict__ Tb,
    const ushort_t* __restrict__ Tf, ushort_t* __restrict__ Lout, int W){
  extern __shared__ __align__(16) ushort_t As[];   // 128x512 bf16
  const int b = blockIdx.x;
  const int c       = (b >> 5) * 8 + (b & 7);      // XCD-affine chain id
  const int rowbase = ((b >> 3) & 3) * 128;
  const int tid  = threadIdx.x;
  const int lane = tid & 63;
  const int wv   = tid >> 6;
  const int l15  = lane & 15;
  const int q4   = lane >> 4;
  const int t0   = c * W;

  load_strip(As, Tb + (size_t)tokens[t0] * MS, rowbase, tid);
  __syncthreads();
  for (int k = 1; k < W; ++k){
    f32x4 acc[4][8];
    #pragma unroll
    for (int mt = 0; mt < 4; ++mt)
      #pragma unroll
      for (int nt = 0; nt < 8; ++nt) acc[mt][nt] = (f32x4){0.f,0.f,0.f,0.f};
    step_mfma(acc, As, Tf + (size_t)tokens[t0 + k] * MS, wv, l15, q4);
    __syncthreads();                   // strip reads done
    if (k < W - 1){
      writeback_lds(As, acc, wv, l15, q4);
      __syncthreads();                 // new strip visible
    } else {
      store_out(Lout + (size_t)c * MS, acc, rowbase, !(c & 1), lane, wv, l15, q4);
    }
  }
}

// One tree level with the same engine: Ldst[j] = Lsrc[2j](RM) @ Lsrc[2j+1](fragT)
__global__ __launch_bounds__(512, 2) void k_tree2(
    const ushort_t* __restrict__ Lsrc, ushort_t* __restrict__ Ldst){
  extern __shared__ __align__(16) ushort_t As[];
  const int j = blockIdx.x >> 2, rowbase = (blockIdx.x & 3) * 128;
  const int tid  = threadIdx.x;
  const int lane = tid & 63;
  const int wv   = tid >> 6;
  const int l15  = lane & 15;
  const int q4   = lane >> 4;
  load_strip(As, Lsrc + (size_t)(2*j) * MS, rowbase, tid);
  __syncthreads();
  f32x4 acc[4][8];
  #pragma unroll
  for (int mt = 0; mt < 4; ++mt)
    #pragma unroll
    for (int nt = 0; nt < 8; ++nt) acc[mt][nt] = (f32x4){0.f,0.f,0.f,0.f};
  step_mfma(acc, As, Lsrc + (size_t)(2*j + 1) * MS, wv, l15, q4);
  store_out(Ldst + (size_t)j * MS, acc, rowbase, !(j & 1), lane, wv, l15, q4);
}

// transfer f32 -> Tb (bf16 row-major) + Tf (bf16 fragment-major transposed)
__global__ __launch_bounds__(256) void k_prep(const float* __restrict__ transfer,
                                              ushort_t* __restrict__ Tb,
                                              ushort_t* __restrict__ Tf){
  __shared__ ushort_t t[32*512];
  const int s = blockIdx.x >> 4;
  const int kk = blockIdx.x & 15;                  // K-band [32kk,+32)
  const int krows = kk * 32;
  const int tid = threadIdx.x;
  for (int idx = tid; idx < 32*512; idx += 256){
    int r = idx >> 9, n = idx & 511;
    ushort_t h = f2bf(transfer[(size_t)s*MS + (size_t)(krows + r)*NSTATE + n]);
    Tb[(size_t)s*MS + (size_t)(krows + r)*NSTATE + n] = h;
    t[r*512 + n] = h;
  }
  __syncthreads();
  for (int idx = tid; idx < 512*4; idx += 256){
    int n = idx >> 2, cc = idx & 3;
    v8s vv;
    #pragma unroll
    for (int jj = 0; jj < 8; ++jj) vv[jj] = (short)t[(cc*8 + jj)*512 + n];
    *(v8s*)&Tf[(size_t)s*MS + ((size_t)(kk*512 + n)*4 + cc)*8] = vv;
  }
}

// ---------------------------------------------------------------------------
// Fallback path (no big-LDS): round-3 gemm_step re-addressed for fragT B.
// ---------------------------------------------------------------------------
__device__ __forceinline__ void gl_lds16(const void* g, void* l){
  __builtin_amdgcn_global_load_lds(
      (const __attribute__((address_space(1))) unsigned int*)g,
      (__attribute__((address_space(3))) unsigned int*)l, 16, 0, 0);
}

__device__ void gemm_step(const ushort_t* __restrict__ A,
                          const ushort_t* __restrict__ Bf,
                          ushort_t* dRM, ushort_t* dT, int rowbase){
  __shared__ __align__(16) ushort_t ldsA[128*64];
  __shared__ __align__(16) ushort_t ldsB[128*64];
  const int tid  = threadIdx.x;
  const int lane = tid & 63;
  const int w    = tid >> 6;
  const int l15  = lane & 15;
  const int koff = (lane >> 4) * 8;

  __threadfence_block();

  for (int p = 0; p < 4; ++p){
    f32x4 acc[2][8];
    #pragma unroll
    for (int rt = 0; rt < 2; ++rt)
      #pragma unroll
      for (int ct = 0; ct < 8; ++ct) acc[rt][ct] = (f32x4){0.f,0.f,0.f,0.f};

    for (int kk = 0; kk < 8; ++kk){
      __syncthreads();
      #pragma unroll
      for (int q = 0; q < 4; ++q){
        int idx = tid + q*256;
        int rr = idx >> 3, cch = idx & 7;
        gl_lds16(&A [(size_t)(rowbase + rr)*NSTATE + kk*64 + cch*8], &ldsA[idx*8]);
        gl_lds16(&Bf[fragT_idx(p*128 + rr, kk*64 + cch*8)], &ldsB[idx*8]);
      }
      __syncthreads();
      #pragma unroll
      for (int kc = 0; kc < 2; ++kc){
        v8s a0 = *(const v8s*)&ldsA[(w*32 +      l15)*64 + kc*32 + koff];
        v8s a1 = *(const v8s*)&ldsA[(w*32 + 16 + l15)*64 + kc*32 + koff];
        #pragma unroll
        for (int ct = 0; ct < 8; ++ct){
          v8s bb = *(const v8s*)&ldsB[(ct*16 + l15)*64 + kc*32 + koff];
          acc[0][ct] = __builtin_amdgcn_mfma_f32_16x16x32_bf16(a0, bb, acc[0][ct], 0,0,0);
          acc[1][ct] = __builtin_amdgcn_mfma_f32_16x16x32_bf16(a1, bb, acc[1][ct], 0,0,0);
        }
      }
    }
    const int rb = rowbase + w*32 + (lane >> 4)*4;
    #pragma unroll
    for (int rt = 0; rt < 2; ++rt)
      #pragma unroll
      for (int ct = 0; ct < 8; ++ct)
        #pragma unroll
        for (int i = 0; i < 4; ++i){
          int grow = rb + rt*16 + i;
          int gcol = p*128 + ct*16 + l15;
          ushort_t h = f2bf(acc[rt][ct][i]);
          if (dRM) dRM[(size_t)grow*NSTATE + gcol] = h;
          if (dT)  dT [fragT_idx(gcol, grow)] = h;
        }
  }
  __syncthreads();
}

__global__ __launch_bounds__(256) void k_chain(const int* __restrict__ tokens,
    const ushort_t* __restrict__ Tb, const ushort_t* __restrict__ Tf,
    ushort_t* ping, ushort_t* pong, ushort_t* Lout, int W){
  const int c = blockIdx.x >> 2;
  const int r = blockIdx.x & 3;
  const int t0 = c * W;
  ushort_t* bufA = ping + (size_t)c * MS;
  ushort_t* bufB = pong + (size_t)c * MS;
  for (int k = 1; k < W; ++k){
    const ushort_t* Asrc = (k == 1) ? Tb + (size_t)tokens[t0] * MS
                                    : (((k - 1) & 1) ? bufA : bufB);
    ushort_t *dRM, *dT;
    if (k == W - 1){
      ushort_t* slot = Lout + (size_t)c * MS;
      dRM = (c & 1) ? nullptr : slot;
      dT  = (c & 1) ? slot    : nullptr;
    } else {
      dRM = (k & 1) ? bufA : bufB; dT = nullptr;
    }
    gemm_step(Asrc, Tf + (size_t)tokens[t0 + k] * MS, dRM, dT, r * 128);
  }
}

__global__ __launch_bounds__(256) void k_tree(const ushort_t* __restrict__ Lsrc,
                                              ushort_t* __restrict__ Ldst){
  const int j = blockIdx.x >> 2, r = blockIdx.x & 3;
  const ushort_t* A  = Lsrc + (size_t)(2*j)     * MS;
  const ushort_t* Bf = Lsrc + (size_t)(2*j + 1) * MS;
  ushort_t* slot = Ldst + (size_t)j * MS;
  gemm_step(A, Bf, (j & 1) ? nullptr : slot, (j & 1) ? slot : nullptr, r * 128);
}

// Boundary vectors u_g via binary decomposition over tree levels baseLvl..11.
// Node index (pos>>p) always even -> row-major form available.
__global__ __launch_bounds__(512) void k_descent(const float* __restrict__ start,
    const ushort_t* __restrict__ lvl4, const ushort_t* __restrict__ Upper,
    float* __restrict__ u, int baseLvl){
  __shared__ float v[NSTATE];
  const int upOff[7] = {0,128,192,224,240,248,252};
  const int g = blockIdx.x, tid = threadIdx.x;
  v[tid] = start[tid];
  __syncthreads();
  int pos = 0;
  for (int p = 11 - baseLvl; p >= 0; --p){
    if ((g >> p) & 1){
      const int L = baseLvl + p;
      const ushort_t* arr = (L == 4) ? lvl4 : (Upper + (size_t)upOff[L-5] * MS);
      const ushort_t* M = arr + (size_t)(pos >> p) * MS;
      float a0=0.f,a1=0.f,a2=0.f,a3=0.f;
      #pragma unroll 4
      for (int i = 0; i < NSTATE; i += 4){
        a0 += v[i  ] * bf2f(M[(size_t)(i  )*NSTATE + tid]);
        a1 += v[i+1] * bf2f(M[(size_t)(i+1)*NSTATE + tid]);
        a2 += v[i+2] * bf2f(M[(size_t)(i+2)*NSTATE + tid]);
        a3 += v[i+3] * bf2f(M[(size_t)(i+3)*NSTATE + tid]);
      }
      __syncthreads();
      v[tid] = (a0+a1)+(a2+a3);
      __syncthreads();
      pos += 1 << p;
    }
  }
  u[(size_t)g*NSTATE + tid] = v[tid];
}

// Per-segment replay: SEG serial f32 vecmat steps from u_g; emission factor
// (v.p)/(sum v); last segment emits `internal` normalized to mass 1.
__global__ __launch_bounds__(512) void k_phase2(const int* __restrict__ tokens,
    const float* __restrict__ u, const ushort_t* __restrict__ Tb,
    const float* __restrict__ probs, float* __restrict__ partials,
    float* __restrict__ out, int SEG){
  __shared__ float v[NSTATE];
  __shared__ float redc[8], redm[8];
  __shared__ float fac, minv;
  const int g = blockIdx.x, tid = threadIdx.x;
  v[tid] = u[(size_t)g*NSTATE + tid];
  float pp = 1.f;
  __syncthreads();
  for (int k = 0; k < SEG; ++k){
    const int tok = tokens[g*SEG + k];
    float a = v[tid];
    float bb = a * probs[(size_t)tok*NSTATE + tid];
    #pragma unroll
    for (int o = 32; o > 0; o >>= 1){
      a  += __shfl_down(a, o);
      bb += __shfl_down(bb, o);
    }
    if ((tid & 63) == 0){ redm[tid >> 6] = a; redc[tid >> 6] = bb; }
    __syncthreads();
    if (tid == 0){
      float m = 0.f, cc = 0.f;
      #pragma unroll
      for (int q = 0; q < 8; ++q){ m += redm[q]; cc += redc[q]; }
      fac = cc / m;
    }
    __syncthreads();
    pp *= fac;
    const ushort_t* M = Tb + (size_t)tok * MS;
    float a0=0.f,a1=0.f,a2=0.f,a3=0.f;
    #pragma unroll 4
    for (int i = 0; i < NSTATE; i += 4){
      a0 += v[i  ] * bf2f(M[(size_t)(i  )*NSTATE + tid]);
      a1 += v[i+1] * bf2f(M[(size_t)(i+1)*NSTATE + tid]);
      a2 += v[i+2] * bf2f(M[(size_t)(i+2)*NSTATE + tid]);
      a3 += v[i+3] * bf2f(M[(size_t)(i+3)*NSTATE + tid]);
    }
    __syncthreads();
    v[tid] = (a0+a1)+(a2+a3);
    __syncthreads();
  }
  if (tid == 0) partials[g] = pp;
  if (g == gridDim.x - 1){
    float a = v[tid];
    #pragma unroll
    for (int o = 32; o > 0; o >>= 1) a += __shfl_down(a, o);
    if ((tid & 63) == 0) redm[tid >> 6] = a;
    __syncthreads();
    if (tid == 0){
      float m = 0.f;
      #pragma unroll
      for (int q = 0; q < 8; ++q) m += redm[q];
      minv = 1.f / m;
    }
    __syncthreads();
    out[tid] = v[tid] * minv;
  }
}

__global__ __launch_bounds__(512) void k_finish(const float* __restrict__ partials,
    const float* __restrict__ finals, float* out, int G){
  __shared__ float red[8];
  const int tid = threadIdx.x;
  float x = out[tid] * finals[tid];
  #pragma unroll
  for (int o = 32; o > 0; o >>= 1) x += __shfl_down(x, o);
  if ((tid & 63) == 0) red[tid >> 6] = x;
  __syncthreads();
  if (tid == 0){
    float s = 0.f;
    for (int q = 0; q < 8; ++q) s += red[q];
    float pp = 1.f;
    for (int q = 0; q < G; ++q) pp *= partials[q];
    out[NSTATE] = pp * s;
  }
}

__global__ __launch_bounds__(512) void k_fallback(const int* __restrict__ tokens,
    const float* __restrict__ start, const float* __restrict__ transfer,
    const float* __restrict__ probs, const float* __restrict__ finals,
    float* out){
  __shared__ float v[NSTATE];
  __shared__ float red[9];
  const int tid = threadIdx.x;
  v[tid] = start[tid];
  float pp = 1.f;
  __syncthreads();
  for (int t = 0; t < LTOK; ++t){
    const int tok = tokens[t];
    float x = v[tid] * probs[(size_t)tok*NSTATE + tid];
    #pragma unroll
    for (int o = 32; o > 0; o >>= 1) x += __shfl_down(x, o);
    if ((tid & 63) == 0) red[tid >> 6] = x;
    __syncthreads();
    if (tid == 0){
      float cc = 0.f;
      for (int q = 0; q < 8; ++q) cc += red[q];
      red[8] = cc;
    }
    __syncthreads();
    pp *= red[8];
    const float* M = transfer + (size_t)tok * MS;
    float acc = 0.f;
    #pragma unroll 8
    for (int i = 0; i < NSTATE; ++i) acc += v[i] * M[(size_t)i*NSTATE + tid];
    __syncthreads();
    v[tid] = acc;
    __syncthreads();
  }
  out[tid] = v[tid];
  float x = v[tid] * finals[tid];
  #pragma unroll
  for (int o = 32; o > 0; o >>= 1) x += __shfl_down(x, o);
  if ((tid & 63) == 0) red[tid >> 6] = x;
  __syncthreads();
  if (tid == 0){
    float s = 0.f;
    for (int q = 0; q < 8; ++q) s += red[q];
    out[NSTATE] = pp * s;
  }
}

extern "C" void kernel_launch(void* const* d_in, const int* in_sizes, int n_in,
                              void* d_out, int out_size, void* d_ws, size_t ws_size,
                              hipStream_t stream) {
  const int*   tokens   = (const int*)  d_in[0];
  const float* start    = (const float*)d_in[1];
  const float* transfer = (const float*)d_in[2];
  const float* probs    = (const float*)d_in[3];
  const float* finals   = (const float*)d_in[4];
  float* out = (float*)d_out;
  (void)in_sizes; (void)n_in; (void)out_size;

  const size_t C2 = MS * 2;
  size_t off = 0;
  const size_t o_Tb    = off; off += C2 * NSYM;    // 64 MiB
  const size_t o_Tf    = off; off += C2 * NSYM;    // 64 MiB
  const size_t o_Upper = off; off += C2 * 254;     // 127 MiB (tree levels 5..11)
  const size_t o_u     = off; off += (size_t)256 * NSTATE * 4;
  const size_t o_part  = off; off += 256 * 4 + 256;
  const size_t common  = off;                      // ~255.4 MiB

  const int LDSBYTES = 128*512*2;                  // 131072
  bool bigLds =
    hipFuncSetAttribute(reinterpret_cast<const void*>(k_chain2),
        hipFuncAttributeMaxDynamicSharedMemorySize, LDSBYTES) == hipSuccess &&
    hipFuncSetAttribute(reinterpret_cast<const void*>(k_tree2),
        hipFuncAttributeMaxDynamicSharedMemorySize, LDSBYTES) == hipSuccess;

  char* ws = (char*)d_ws;
  ushort_t* Tb    = (ushort_t*)(ws + o_Tb);
  ushort_t* Tf    = (ushort_t*)(ws + o_Tf);
  ushort_t* Upper = (ushort_t*)(ws + o_Upper);
  float*    u     = (float*)   (ws + o_u);
  float*    parts = (float*)   (ws + o_part);

  const int upOff[7] = {0,128,192,224,240,248,252};
  ushort_t* lvl[12] = {nullptr};
  for (int l = 5; l <= 11; ++l) lvl[l] = Upper + (size_t)upOff[l-5] * MS;

  int W = 0, sLvl = 0;
  size_t oo = common;
  if (bigLds){
    if      (ws_size >= common + C2 * (512 + 256)) { W = 8;  sLvl = 3; }
    else if (ws_size >= common + C2 * 256)         { W = 16; sLvl = 4; }
    else if (ws_size >= common)                    { W = 32; sLvl = 5; }
    if (W){
      if (W == 8) { lvl[3] = (ushort_t*)(ws + oo); oo += C2 * 512; }
      if (W <= 16){ lvl[4] = (ushort_t*)(ws + oo); oo += C2 * 256; }
    }
  } else {
    if (ws_size >= common + C2 * 256) { W = 32; sLvl = 5; }
  }
  if (!W){
    k_fallback<<<1, 512, 0, stream>>>(tokens, start, transfer, probs, finals, out);
    return;
  }
  const int nchain = LTOK / W;
  const int G    = lvl[4] ? 256 : 128;
  const int SEGc = LTOK / G;
  const int baseLvl = lvl[4] ? 4 : 5;

  k_prep<<<NSYM * 16, 256, 0, stream>>>(transfer, Tb, Tf);
  if (bigLds){
    k_chain2<<<nchain * 4, 512, LDSBYTES, stream>>>(tokens, Tb, Tf, lvl[sLvl], W);
    for (int l = sLvl; l < 11; ++l){
      const int cntNext = LTOK >> (l + 1);
      k_tree2<<<cntNext * 4, 512, LDSBYTES, stream>>>(lvl[l], lvl[l + 1]);
    }
  } else {
    ushort_t* ping = (ushort_t*)(ws + oo); oo += C2 * nchain;
    ushort_t* pong = (ushort_t*)(ws + oo); oo += C2 * nchain;
    k_chain<<<nchain * 4, 256, 0, stream>>>(tokens, Tb, Tf, ping, pong, lvl[sLvl], W);
    for (int l = sLvl; l < 11; ++l){
      const int cntNext = LTOK >> (l + 1);
      k_tree<<<cntNext * 4, 256, 0, stream>>>(lvl[l], lvl[l + 1]);
    }
  }
  k_descent<<<G, 512, 0, stream>>>(start, lvl[4], Upper, u, baseLvl);
  k_phase2 <<<G, 512, 0, stream>>>(tokens, u, Tb, probs, parts, out, SEGc);
  k_finish <<<1, 512, 0, stream>>>(parts, finals, out, G);
}

// Round 7
// 1783.261 us; speedup vs baseline: 3.2852x; 1.0469x over previous
//
#include <hip/hip_runtime.h>
#include <stdint.h>

// AutomatonNetwork: 4096-step vecmat chain lifted to a bf16 MFMA product tree.
// Round-7: 64-row LDS strips (64 KiB) -> 2 independent WGs per CU (16
// waves/CU vs 8): barrier drains of one WG are hidden by the other WG's MFMA.
// acc 4x4 f32x4 (64 VGPR) under __launch_bounds__(512,4) to hold 4 waves/SIMD.
// Token/odd-node matrices remain FRAGMENT-MAJOR (Tf): wave A-frag = one
// contiguous coalesced 1 KiB global load, zero per-kk barriers. Phase-2
// replay now reads Tf too: per-column k-runs of 32 are contiguous -> b128
// vector loads instead of 512 scalar loads per step.
// Numerics: emission factors (v.p)/(sum v) cancel bf16 mass drift (proven,
// absmax 1.5e-5 vs 4e-3 threshold, rounds 2-6).

typedef unsigned short ushort_t;
typedef __attribute__((ext_vector_type(8))) short v8s;    // 8 bf16 MFMA frag
typedef __attribute__((ext_vector_type(4))) float f32x4;  // MFMA 16x16 acc

#define NSTATE 512
#define NSYM   128
#define LTOK   4096
#define MS     ((size_t)NSTATE*NSTATE)

__device__ __forceinline__ ushort_t f2bf(float f){
  unsigned u = __float_as_uint(f);
  u = u + 0x7FFFu + ((u >> 16) & 1u);    // RNE
  return (ushort_t)(u >> 16);
}
__device__ __forceinline__ float bf2f(ushort_t h){
  return __uint_as_float(((unsigned)h) << 16);
}
// fragment-major: element (m, k) of M^T (i.e. M[k][m]) at:
__device__ __forceinline__ size_t fragT_idx(int m, int k){
  return ((size_t)((k >> 5)*512 + m)*4 + ((k >> 3) & 3))*8 + (k & 7);
}

// ---------------------------------------------------------------------------
// 64-row engine. Strip = 64 rows x 512 cols of the running product, LDS-
// resident, swizzled (chunk p holds true chunk p^(n&7)). One step computes
// D = Btok^T(512x512) * Strip^T: wave wv owns C cols [64wv,+64).
//   A-frag: global fragT, contiguous per wave (base + kk*16384 + mt*512)
//   B-frag: strip row n = nt*16+l15, chunk kk*4+q4 (xor n&7)
//   D: acc[mt][nt][i] = newstrip[n][wv*64+mt*16+q4*4+i]
// Layouts HW-proven rounds 2-6.
// ---------------------------------------------------------------------------
__device__ __forceinline__ void step_mfma64(f32x4 acc[4][4],
    const ushort_t* __restrict__ As, const ushort_t* __restrict__ Bf,
    int wv, int l15, int q4){
  const ushort_t* base = Bf + ((size_t)(wv*64 + l15)*4 + q4)*8;
  v8s aA[4], aN[4];
  #pragma unroll
  for (int mt = 0; mt < 4; ++mt) aA[mt] = *(const v8s*)&base[mt*512];
  #pragma unroll
  for (int kk = 0; kk < 16; ++kk){
    if (kk < 15){
      #pragma unroll
      for (int mt = 0; mt < 4; ++mt)
        aN[mt] = *(const v8s*)&base[(size_t)(kk+1)*16384 + mt*512];
    }
    #pragma unroll
    for (int nt = 0; nt < 4; ++nt){
      int n  = nt*16 + l15;
      int ch = kk*4 + q4;
      v8s bf = *(const v8s*)&As[n*512 + ((ch ^ (n & 7))*8)];
      #pragma unroll
      for (int mt = 0; mt < 4; ++mt)
        acc[mt][nt] = __builtin_amdgcn_mfma_f32_16x16x32_bf16(aA[mt], bf, acc[mt][nt], 0,0,0);
    }
    #pragma unroll
    for (int mt = 0; mt < 4; ++mt) aA[mt] = aN[mt];
  }
}

__device__ __forceinline__ void load_strip64(ushort_t* As,
    const ushort_t* __restrict__ src, int rowbase, int tid){
  #pragma unroll
  for (int q = 0; q < 8; ++q){
    int F = tid + q*512;
    int m = F >> 6, p = F & 63;
    *(v8s*)&As[m*512 + p*8] =
      *(const v8s*)&src[(size_t)(rowbase + m)*NSTATE + ((p ^ (m & 7))*8)];
  }
}

__device__ __forceinline__ void writeback64(ushort_t* As, f32x4 acc[4][4],
    int wv, int l15, int q4){
  #pragma unroll
  for (int nt = 0; nt < 4; ++nt){
    int n = nt*16 + l15;
    #pragma unroll
    for (int mt = 0; mt < 4; ++mt){
      int col = wv*64 + mt*16 + q4*4;
      ushort4 h;
      h.x = f2bf(acc[mt][nt][0]); h.y = f2bf(acc[mt][nt][1]);
      h.z = f2bf(acc[mt][nt][2]); h.w = f2bf(acc[mt][nt][3]);
      int p = (col >> 3) ^ (n & 7);
      *(ushort4*)&As[n*512 + p*8 + (col & 7)] = h;
    }
  }
}

// final store: even -> row-major; odd -> fragment-major transposed
__device__ __forceinline__ void store_out64(ushort_t* slot, f32x4 acc[4][4],
    int rowbase, bool even, int lane, int wv, int l15, int q4){
  if (even){
    #pragma unroll
    for (int nt = 0; nt < 4; ++nt){
      int grow = rowbase + nt*16 + l15;
      #pragma unroll
      for (int mt = 0; mt < 4; ++mt){
        int gcol = wv*64 + mt*16 + q4*4;
        ushort4 h;
        h.x = f2bf(acc[mt][nt][0]); h.y = f2bf(acc[mt][nt][1]);
        h.z = f2bf(acc[mt][nt][2]); h.w = f2bf(acc[mt][nt][3]);
        *(ushort4*)&slot[(size_t)grow*NSTATE + gcol] = h;
      }
    }
  } else {
    // 4x4 quad butterfly (HW-proven rounds 5-6): lane ends with
    // d[i] = C[G0+i][mcol], contiguous in fragT (k = G0..G0+3)
    #pragma unroll
    for (int nt = 0; nt < 4; ++nt){
      int G0 = rowbase + nt*16 + (l15 & 12);
      #pragma unroll
      for (int mt = 0; mt < 4; ++mt){
        float v0 = acc[mt][nt][0], v1 = acc[mt][nt][1];
        float v2 = acc[mt][nt][2], v3 = acc[mt][nt][3];
        float s0 = __shfl_xor(v0, 2), s1 = __shfl_xor(v1, 2);
        float s2 = __shfl_xor(v2, 2), s3 = __shfl_xor(v3, 2);
        const bool h2 = lane & 2;
        float c0 = h2 ? s2 : v0, c1 = h2 ? s3 : v1;
        float c2 = h2 ? v2 : s0, c3 = h2 ? v3 : s1;
        float u0 = __shfl_xor(c0, 1), u1 = __shfl_xor(c1, 1);
        float u2 = __shfl_xor(c2, 1), u3 = __shfl_xor(c3, 1);
        const bool h1 = lane & 1;
        float d0 = h1 ? u1 : c0, d1 = h1 ? c1 : u0;
        float d2 = h1 ? u3 : c2, d3 = h1 ? c3 : u2;
        int mcol = wv*64 + mt*16 + q4*4 + (lane & 3);
        ushort4 h;
        h.x = f2bf(d0); h.y = f2bf(d1); h.z = f2bf(d2); h.w = f2bf(d3);
        *(ushort4*)&slot[fragT_idx(mcol, G0)] = h;
      }
    }
  }
}

// Chains: WG (c, strip) holds 64 rows of chain c's product in LDS across all
// W-1 steps. 8 strips of a chain share one XCD (b%8 = XCD affinity).
__global__ __launch_bounds__(512, 4) void k_chain3(
    const int* __restrict__ tokens, const ushort_t* __restrict__ Tb,
    const ushort_t* __restrict__ Tf, ushort_t* __restrict__ Lout, int W){
  extern __shared__ __align__(16) ushort_t As[];   // 64x512 bf16
  const int b = blockIdx.x;
  const int c       = (b >> 6) * 8 + (b & 7);
  const int rowbase = ((b >> 3) & 7) * 64;
  const int tid  = threadIdx.x;
  const int lane = tid & 63;
  const int wv   = tid >> 6;
  const int l15  = lane & 15;
  const int q4   = lane >> 4;
  const int t0   = c * W;

  load_strip64(As, Tb + (size_t)tokens[t0] * MS, rowbase, tid);
  __syncthreads();
  for (int k = 1; k < W; ++k){
    f32x4 acc[4][4];
    #pragma unroll
    for (int mt = 0; mt < 4; ++mt)
      #pragma unroll
      for (int nt = 0; nt < 4; ++nt) acc[mt][nt] = (f32x4){0.f,0.f,0.f,0.f};
    step_mfma64(acc, As, Tf + (size_t)tokens[t0 + k] * MS, wv, l15, q4);
    __syncthreads();                   // strip reads done
    if (k < W - 1){
      writeback64(As, acc, wv, l15, q4);
      __syncthreads();                 // new strip visible
    } else {
      store_out64(Lout + (size_t)c * MS, acc, rowbase, !(c & 1), lane, wv, l15, q4);
    }
  }
}

// One tree level: Ldst[j] = Lsrc[2j](RM) @ Lsrc[2j+1](fragT), 8 strips/node.
__global__ __launch_bounds__(512, 4) void k_tree3(
    const ushort_t* __restrict__ Lsrc, ushort_t* __restrict__ Ldst){
  extern __shared__ __align__(16) ushort_t As[];
  const int b = blockIdx.x;
  int j, strip;
  if (gridDim.x >= 64){ j = (b >> 6) * 8 + (b & 7); strip = (b >> 3) & 7; }
  else                { j = b >> 3;                  strip = b & 7; }
  const int rowbase = strip * 64;
  const int tid  = threadIdx.x;
  const int lane = tid & 63;
  const int wv   = tid >> 6;
  const int l15  = lane & 15;
  const int q4   = lane >> 4;
  load_strip64(As, Lsrc + (size_t)(2*j) * MS, rowbase, tid);
  __syncthreads();
  f32x4 acc[4][4];
  #pragma unroll
  for (int mt = 0; mt < 4; ++mt)
    #pragma unroll
    for (int nt = 0; nt < 4; ++nt) acc[mt][nt] = (f32x4){0.f,0.f,0.f,0.f};
  step_mfma64(acc, As, Lsrc + (size_t)(2*j + 1) * MS, wv, l15, q4);
  store_out64(Ldst + (size_t)j * MS, acc, rowbase, !(j & 1), lane, wv, l15, q4);
}

// transfer f32 -> Tb (bf16 row-major) + Tf (bf16 fragment-major transposed)
__global__ __launch_bounds__(256) void k_prep(const float* __restrict__ transfer,
                                              ushort_t* __restrict__ Tb,
                                              ushort_t* __restrict__ Tf){
  __shared__ ushort_t t[32*512];
  const int s = blockIdx.x >> 4;
  const int kk = blockIdx.x & 15;                  // K-band [32kk,+32)
  const int krows = kk * 32;
  const int tid = threadIdx.x;
  for (int idx = tid; idx < 32*512; idx += 256){
    int r = idx >> 9, n = idx & 511;
    ushort_t h = f2bf(transfer[(size_t)s*MS + (size_t)(krows + r)*NSTATE + n]);
    Tb[(size_t)s*MS + (size_t)(krows + r)*NSTATE + n] = h;
    t[r*512 + n] = h;
  }
  __syncthreads();
  for (int idx = tid; idx < 512*4; idx += 256){
    int n = idx >> 2, cc = idx & 3;
    v8s vv;
    #pragma unroll
    for (int jj = 0; jj < 8; ++jj) vv[jj] = (short)t[(cc*8 + jj)*512 + n];
    *(v8s*)&Tf[(size_t)s*MS + ((size_t)(kk*512 + n)*4 + cc)*8] = vv;
  }
}

// ---------------------------------------------------------------------------
// Fallback path (no big-LDS): proven round-6 gemm_step with fragT B.
// ---------------------------------------------------------------------------
__device__ __forceinline__ void gl_lds16(const void* g, void* l){
  __builtin_amdgcn_global_load_lds(
      (const __attribute__((address_space(1))) unsigned int*)g,
      (__attribute__((address_space(3))) unsigned int*)l, 16, 0, 0);
}

__device__ void gemm_step(const ushort_t* __restrict__ A,
                          const ushort_t* __restrict__ Bf,
                          ushort_t* dRM, ushort_t* dT, int rowbase){
  __shared__ __align__(16) ushort_t ldsA[128*64];
  __shared__ __align__(16) ushort_t ldsB[128*64];
  const int tid  = threadIdx.x;
  const int lane = tid & 63;
  const int w    = tid >> 6;
  const int l15  = lane & 15;
  const int koff = (lane >> 4) * 8;

  __threadfence_block();

  for (int p = 0; p < 4; ++p){
    f32x4 acc[2][8];
    #pragma unroll
    for (int rt = 0; rt < 2; ++rt)
      #pragma unroll
      for (int ct = 0; ct < 8; ++ct) acc[rt][ct] = (f32x4){0.f,0.f,0.f,0.f};

    for (int kk = 0; kk < 8; ++kk){
      __syncthreads();
      #pragma unroll
      for (int q = 0; q < 4; ++q){
        int idx = tid + q*256;
        int rr = idx >> 3, cch = idx & 7;
        gl_lds16(&A [(size_t)(rowbase + rr)*NSTATE + kk*64 + cch*8], &ldsA[idx*8]);
        gl_lds16(&Bf[fragT_idx(p*128 + rr, kk*64 + cch*8)], &ldsB[idx*8]);
      }
      __syncthreads();
      #pragma unroll
      for (int kc = 0; kc < 2; ++kc){
        v8s a0 = *(const v8s*)&ldsA[(w*32 +      l15)*64 + kc*32 + koff];
        v8s a1 = *(const v8s*)&ldsA[(w*32 + 16 + l15)*64 + kc*32 + koff];
        #pragma unroll
        for (int ct = 0; ct < 8; ++ct){
          v8s bb = *(const v8s*)&ldsB[(ct*16 + l15)*64 + kc*32 + koff];
          acc[0][ct] = __builtin_amdgcn_mfma_f32_16x16x32_bf16(a0, bb, acc[0][ct], 0,0,0);
          acc[1][ct] = __builtin_amdgcn_mfma_f32_16x16x32_bf16(a1, bb, acc[1][ct], 0,0,0);
        }
      }
    }
    const int rb = rowbase + w*32 + (lane >> 4)*4;
    #pragma unroll
    for (int rt = 0; rt < 2; ++rt)
      #pragma unroll
      for (int ct = 0; ct < 8; ++ct)
        #pragma unroll
        for (int i = 0; i < 4; ++i){
          int grow = rb + rt*16 + i;
          int gcol = p*128 + ct*16 + l15;
          ushort_t h = f2bf(acc[rt][ct][i]);
          if (dRM) dRM[(size_t)grow*NSTATE + gcol] = h;
          if (dT)  dT [fragT_idx(gcol, grow)] = h;
        }
  }
  __syncthreads();
}

__global__ __launch_bounds__(256) void k_chain(const int* __restrict__ tokens,
    const ushort_t* __restrict__ Tb, const ushort_t* __restrict__ Tf,
    ushort_t* ping, ushort_t* pong, ushort_t* Lout, int W){
  const int c = blockIdx.x >> 2;
  const int r = blockIdx.x & 3;
  const int t0 = c * W;
  ushort_t* bufA = ping + (size_t)c * MS;
  ushort_t* bufB = pong + (size_t)c * MS;
  for (int k = 1; k < W; ++k){
    const ushort_t* Asrc = (k == 1) ? Tb + (size_t)tokens[t0] * MS
                                    : (((k - 1) & 1) ? bufA : bufB);
    ushort_t *dRM, *dT;
    if (k == W - 1){
      ushort_t* slot = Lout + (size_t)c * MS;
      dRM = (c & 1) ? nullptr : slot;
      dT  = (c & 1) ? slot    : nullptr;
    } else {
      dRM = (k & 1) ? bufA : bufB; dT = nullptr;
    }
    gemm_step(Asrc, Tf + (size_t)tokens[t0 + k] * MS, dRM, dT, r * 128);
  }
}

__global__ __launch_bounds__(256) void k_tree(const ushort_t* __restrict__ Lsrc,
                                              ushort_t* __restrict__ Ldst){
  const int j = blockIdx.x >> 2, r = blockIdx.x & 3;
  const ushort_t* A  = Lsrc + (size_t)(2*j)     * MS;
  const ushort_t* Bf = Lsrc + (size_t)(2*j + 1) * MS;
  ushort_t* slot = Ldst + (size_t)j * MS;
  gemm_step(A, Bf, (j & 1) ? nullptr : slot, (j & 1) ? slot : nullptr, r * 128);
}

// Boundary vectors u_g via binary decomposition over tree levels baseLvl..11.
// Node index (pos>>p) always even -> row-major form available.
__global__ __launch_bounds__(512) void k_descent(const float* __restrict__ start,
    const ushort_t* __restrict__ lvl4, const ushort_t* __restrict__ Upper,
    float* __restrict__ u, int baseLvl){
  __shared__ float v[NSTATE];
  const int upOff[7] = {0,128,192,224,240,248,252};
  const int g = blockIdx.x, tid = threadIdx.x;
  v[tid] = start[tid];
  __syncthreads();
  int pos = 0;
  for (int p = 11 - baseLvl; p >= 0; --p){
    if ((g >> p) & 1){
      const int L = baseLvl + p;
      const ushort_t* arr = (L == 4) ? lvl4 : (Upper + (size_t)upOff[L-5] * MS);
      const ushort_t* M = arr + (size_t)(pos >> p) * MS;
      float a0=0.f,a1=0.f,a2=0.f,a3=0.f;
      #pragma unroll 4
      for (int i = 0; i < NSTATE; i += 4){
        a0 += v[i  ] * bf2f(M[(size_t)(i  )*NSTATE + tid]);
        a1 += v[i+1] * bf2f(M[(size_t)(i+1)*NSTATE + tid]);
        a2 += v[i+2] * bf2f(M[(size_t)(i+2)*NSTATE + tid]);
        a3 += v[i+3] * bf2f(M[(size_t)(i+3)*NSTATE + tid]);
      }
      __syncthreads();
      v[tid] = (a0+a1)+(a2+a3);
      __syncthreads();
      pos += 1 << p;
    }
  }
  u[(size_t)g*NSTATE + tid] = v[tid];
}

// Per-segment replay with fragT vector loads: thread tid = output column m;
// M[k][m] for 32 consecutive k is 64 contiguous bytes in Tf.
__global__ __launch_bounds__(512) void k_phase2(const int* __restrict__ tokens,
    const float* __restrict__ u, const ushort_t* __restrict__ Tf,
    const float* __restrict__ probs, float* __restrict__ partials,
    float* __restrict__ out, int SEG){
  __shared__ float v[NSTATE];
  __shared__ float redc[8], redm[8];
  __shared__ float fac, minv;
  const int g = blockIdx.x, tid = threadIdx.x;
  v[tid] = u[(size_t)g*NSTATE + tid];
  float pp = 1.f;
  __syncthreads();
  for (int k = 0; k < SEG; ++k){
    const int tok = tokens[g*SEG + k];
    float a = v[tid];
    float bb = a * probs[(size_t)tok*NSTATE + tid];
    #pragma unroll
    for (int o = 32; o > 0; o >>= 1){
      a  += __shfl_down(a, o);
      bb += __shfl_down(bb, o);
    }
    if ((tid & 63) == 0){ redm[tid >> 6] = a; redc[tid >> 6] = bb; }
    __syncthreads();
    if (tid == 0){
      float m = 0.f, cc = 0.f;
      #pragma unroll
      for (int q = 0; q < 8; ++q){ m += redm[q]; cc += redc[q]; }
      fac = cc / m;
    }
    __syncthreads();
    pp *= fac;
    const ushort_t* Mf = Tf + (size_t)tok * MS + (size_t)tid * 32;
    float a0=0.f,a1=0.f,a2=0.f,a3=0.f;
    for (int bnd = 0; bnd < 16; ++bnd){
      const v8s* pv = (const v8s*)&Mf[(size_t)bnd*16384];
      v8s h0 = pv[0], h1 = pv[1], h2 = pv[2], h3 = pv[3];
      const float* vb = &v[bnd*32];
      #pragma unroll
      for (int j = 0; j < 8; ++j){
        a0 += vb[j     ] * bf2f((ushort_t)h0[j]);
        a1 += vb[j +  8] * bf2f((ushort_t)h1[j]);
        a2 += vb[j + 16] * bf2f((ushort_t)h2[j]);
        a3 += vb[j + 24] * bf2f((ushort_t)h3[j]);
      }
    }
    __syncthreads();
    v[tid] = (a0+a1)+(a2+a3);
    __syncthreads();
  }
  if (tid == 0) partials[g] = pp;
  if (g == gridDim.x - 1){
    float a = v[tid];
    #pragma unroll
    for (int o = 32; o > 0; o >>= 1) a += __shfl_down(a, o);
    if ((tid & 63) == 0) redm[tid >> 6] = a;
    __syncthreads();
    if (tid == 0){
      float m = 0.f;
      #pragma unroll
      for (int q = 0; q < 8; ++q) m += redm[q];
      minv = 1.f / m;
    }
    __syncthreads();
    out[tid] = v[tid] * minv;
  }
}

__global__ __launch_bounds__(512) void k_finish(const float* __restrict__ partials,
    const float* __restrict__ finals, float* out, int G){
  __shared__ float red[8];
  const int tid = threadIdx.x;
  float x = out[tid] * finals[tid];
  #pragma unroll
  for (int o = 32; o > 0; o >>= 1) x += __shfl_down(x, o);
  if ((tid & 63) == 0) red[tid >> 6] = x;
  __syncthreads();
  if (tid == 0){
    float s = 0.f;
    for (int q = 0; q < 8; ++q) s += red[q];
    float pp = 1.f;
    for (int q = 0; q < G; ++q) pp *= partials[q];
    out[NSTATE] = pp * s;
  }
}

__global__ __launch_bounds__(512) void k_fallback(const int* __restrict__ tokens,
    const float* __restrict__ start, const float* __restrict__ transfer,
    const float* __restrict__ probs, const float* __restrict__ finals,
    float* out){
  __shared__ float v[NSTATE];
  __shared__ float red[9];
  const int tid = threadIdx.x;
  v[tid] = start[tid];
  float pp = 1.f;
  __syncthreads();
  for (int t = 0; t < LTOK; ++t){
    const int tok = tokens[t];
    float x = v[tid] * probs[(size_t)tok*NSTATE + tid];
    #pragma unroll
    for (int o = 32; o > 0; o >>= 1) x += __shfl_down(x, o);
    if ((tid & 63) == 0) red[tid >> 6] = x;
    __syncthreads();
    if (tid == 0){
      float cc = 0.f;
      for (int q = 0; q < 8; ++q) cc += red[q];
      red[8] = cc;
    }
    __syncthreads();
    pp *= red[8];
    const float* M = transfer + (size_t)tok * MS;
    float acc = 0.f;
    #pragma unroll 8
    for (int i = 0; i < NSTATE; ++i) acc += v[i] * M[(size_t)i*NSTATE + tid];
    __syncthreads();
    v[tid] = acc;
    __syncthreads();
  }
  out[tid] = v[tid];
  float x = v[tid] * finals[tid];
  #pragma unroll
  for (int o = 32; o > 0; o >>= 1) x += __shfl_down(x, o);
  if ((tid & 63) == 0) red[tid >> 6] = x;
  __syncthreads();
  if (tid == 0){
    float s = 0.f;
    for (int q = 0; q < 8; ++q) s += red[q];
    out[NSTATE] = pp * s;
  }
}

extern "C" void kernel_launch(void* const* d_in, const int* in_sizes, int n_in,
                              void* d_out, int out_size, void* d_ws, size_t ws_size,
                              hipStream_t stream) {
  const int*   tokens   = (const int*)  d_in[0];
  const float* start    = (const float*)d_in[1];
  const float* transfer = (const float*)d_in[2];
  const float* probs    = (const float*)d_in[3];
  const float* finals   = (const float*)d_in[4];
  float* out = (float*)d_out;
  (void)in_sizes; (void)n_in; (void)out_size;

  const size_t C2 = MS * 2;
  size_t off = 0;
  const size_t o_Tb    = off; off += C2 * NSYM;    // 64 MiB
  const size_t o_Tf    = off; off += C2 * NSYM;    // 64 MiB
  const size_t o_Upper = off; off += C2 * 254;     // 127 MiB (tree levels 5..11)
  const size_t o_u     = off; off += (size_t)256 * NSTATE * 4;
  const size_t o_part  = off; off += 256 * 4 + 256;
  const size_t common  = off;                      // ~255.4 MiB

  const int LDSBYTES = 64*512*2;                   // 65536
  bool bigLds =
    hipFuncSetAttribute(reinterpret_cast<const void*>(k_chain3),
        hipFuncAttributeMaxDynamicSharedMemorySize, LDSBYTES) == hipSuccess &&
    hipFuncSetAttribute(reinterpret_cast<const void*>(k_tree3),
        hipFuncAttributeMaxDynamicSharedMemorySize, LDSBYTES) == hipSuccess;

  char* ws = (char*)d_ws;
  ushort_t* Tb    = (ushort_t*)(ws + o_Tb);
  ushort_t* Tf    = (ushort_t*)(ws + o_Tf);
  ushort_t* Upper = (ushort_t*)(ws + o_Upper);
  float*    u     = (float*)   (ws + o_u);
  float*    parts = (float*)   (ws + o_part);

  const int upOff[7] = {0,128,192,224,240,248,252};
  ushort_t* lvl[12] = {nullptr};
  for (int l = 5; l <= 11; ++l) lvl[l] = Upper + (size_t)upOff[l-5] * MS;

  int W = 0, sLvl = 0;
  size_t oo = common;
  if (bigLds){
    if      (ws_size >= common + C2 * (512 + 256)) { W = 8;  sLvl = 3; }
    else if (ws_size >= common + C2 * 256)         { W = 16; sLvl = 4; }
    else if (ws_size >= common)                    { W = 32; sLvl = 5; }
    if (W){
      if (W == 8) { lvl[3] = (ushort_t*)(ws + oo); oo += C2 * 512; }
      if (W <= 16){ lvl[4] = (ushort_t*)(ws + oo); oo += C2 * 256; }
    }
  } else {
    if (ws_size >= common + C2 * 256) { W = 32; sLvl = 5; }
  }
  if (!W){
    k_fallback<<<1, 512, 0, stream>>>(tokens, start, transfer, probs, finals, out);
    return;
  }
  const int nchain = LTOK / W;
  const int G    = lvl[4] ? 256 : 128;
  const int SEGc = LTOK / G;
  const int baseLvl = lvl[4] ? 4 : 5;

  k_prep<<<NSYM * 16, 256, 0, stream>>>(transfer, Tb, Tf);
  if (bigLds){
    k_chain3<<<nchain * 8, 512, LDSBYTES, stream>>>(tokens, Tb, Tf, lvl[sLvl], W);
    for (int l = sLvl; l < 11; ++l){
      const int cntNext = LTOK >> (l + 1);
      k_tree3<<<cntNext * 8, 512, LDSBYTES, stream>>>(lvl[l], lvl[l + 1]);
    }
  } else {
    ushort_t* ping = (ushort_t*)(ws + oo); oo += C2 * nchain;
    ushort_t* pong = (ushort_t*)(ws + oo); oo += C2 * nchain;
    k_chain<<<nchain * 4, 256, 0, stream>>>(tokens, Tb, Tf, ping, pong, lvl[sLvl], W);
    for (int l = sLvl; l < 11; ++l){
      const int cntNext = LTOK >> (l + 1);
      k_tree<<<cntNext * 4, 256, 0, stream>>>(lvl[l], lvl[l + 1]);
    }
  }
  k_descent<<<G, 512, 0, stream>>>(start, lvl[4], Upper, u, baseLvl);
  k_phase2 <<<G, 512, 0, stream>>>(tokens, u, Tf, probs, parts, out, SEGc);
  k_finish <<<1, 512, 0, stream>>>(parts, finals, out, G);
}